// Round 2
// baseline (2258.620 us; speedup 1.0000x reference)
//
#include <hip/hip_runtime.h>
#include <cmath>

#pragma clang fp contract(off)

#define NPRIORS 131072
#define NIMG 16
#define KSEL 5000
#define TOPK 750
#define SORTN 8192
#define NBINS 1024
#define NSUB 8
#define NMASK ((KSEL + 63) / 64)   // 79
#define MW 80                      // mask words per row (padded)

// ---------------- workspace layout ----------------
// pairs   : u64  [NIMG][SORTN]     offset 0          size 1,048,576
// mcount  : int  [NIMG]            offset 1,048,576  size 64 (pad 256)
// sboxes  : f4   [NIMG][KSEL]      offset 1,048,832  size 1,280,000
// sscores : f32  [NIMG][KSEL]      offset 2,328,832  size 320,000
// mask    : u64  [NIMG][KSEL][MW]  offset 2,649,088  size 51,200,000
#define WS_PAIRS 0
#define WS_MCNT 1048576
#define WS_BOXES 1048832
#define WS_SCORES 2328832
#define WS_MASK 2649088
#define WS_NEEDED (WS_MASK + (size_t)NIMG * KSEL * MW * 8)

// ============ Kernel 1: exact top-KSEL selection via 2-level histogram ============
__global__ __launch_bounds__(1024) void select_kernel(const float* __restrict__ conf,
                                                      unsigned long long* __restrict__ pairs,
                                                      int* __restrict__ mcount) {
#pragma clang fp contract(off)
  const int img = blockIdx.x;
  const int tid = threadIdx.x;
  __shared__ unsigned int h[NSUB][NBINS];
  __shared__ unsigned int scan[NBINS];
  __shared__ unsigned int s_b1, s_base, s_cutoff, s_cnt;

  const float* cbase = conf + (size_t)img * NPRIORS * 2 + 1;  // class-1 scores, stride 2
  const int sub = (tid >> 6) & (NSUB - 1);

  // ---- pass 1: histogram on u>>22 ----
  for (int i = tid; i < NSUB * NBINS; i += 1024) ((unsigned int*)h)[i] = 0;
  __syncthreads();
  for (int p = tid; p < NPRIORS; p += 1024) {
    float sc = cbase[(size_t)p * 2];
    unsigned int u = (sc > 0.05f) ? (__float_as_uint(sc) | 0x80000000u) : 0u;
    if (u) atomicAdd(&h[sub][u >> 22], 1u);
  }
  __syncthreads();
  unsigned int cnt = 0;
  for (int s = 0; s < NSUB; s++) cnt += h[s][tid];
  scan[tid] = cnt;
  if (tid == 0) s_b1 = 0xFFFFFFFFu;
  __syncthreads();
  // inclusive suffix scan (Hillis-Steele)
  for (int off = 1; off < NBINS; off <<= 1) {
    unsigned int v = (tid + off < NBINS) ? scan[tid + off] : 0u;
    __syncthreads();
    scan[tid] += v;
    __syncthreads();
  }
  unsigned int sfx = scan[tid];
  if (sfx >= KSEL && (sfx - cnt) < KSEL) { s_b1 = (unsigned int)tid; s_base = sfx - cnt; }
  __syncthreads();
  unsigned int b1 = s_b1;
  unsigned int cutoff;
  if (b1 == 0xFFFFFFFFu) {
    cutoff = 1u;  // fewer than KSEL above threshold: take all u>0
  } else {
    // ---- pass 2: refine boundary bin on bits (u>>12)&1023 ----
    for (int i = tid; i < NSUB * NBINS; i += 1024) ((unsigned int*)h)[i] = 0;
    __syncthreads();
    for (int p = tid; p < NPRIORS; p += 1024) {
      float sc = cbase[(size_t)p * 2];
      unsigned int u = (sc > 0.05f) ? (__float_as_uint(sc) | 0x80000000u) : 0u;
      if (u && (u >> 22) == b1) atomicAdd(&h[sub][(u >> 12) & (NBINS - 1)], 1u);
    }
    __syncthreads();
    unsigned int cnt2 = 0;
    for (int s = 0; s < NSUB; s++) cnt2 += h[s][tid];
    scan[tid] = cnt2;
    __syncthreads();
    for (int off = 1; off < NBINS; off <<= 1) {
      unsigned int v = (tid + off < NBINS) ? scan[tid + off] : 0u;
      __syncthreads();
      scan[tid] += v;
      __syncthreads();
    }
    unsigned int base = s_base;
    unsigned int sfx2 = scan[tid];
    if (base + sfx2 >= KSEL && (base + sfx2 - cnt2) < KSEL)
      s_cutoff = (b1 << 22) | ((unsigned int)tid << 12);
    __syncthreads();
    cutoff = s_cutoff;
  }

  // ---- pass 3: compact (u, flipped idx) keys ----
  if (tid == 0) s_cnt = 0;
  __syncthreads();
  unsigned long long* mypairs = pairs + (size_t)img * SORTN;
  for (int p = tid; p < NPRIORS; p += 1024) {
    float sc = cbase[(size_t)p * 2];
    unsigned int u = (sc > 0.05f) ? (__float_as_uint(sc) | 0x80000000u) : 0u;
    if (u >= cutoff && u != 0u) {
      unsigned int pos = atomicAdd(&s_cnt, 1u);
      if (pos < SORTN)
        mypairs[pos] = ((unsigned long long)u << 32) | (unsigned long long)(0xFFFFFFFFu - (unsigned int)p);
    }
  }
  __syncthreads();
  if (tid == 0) mcount[img] = (int)min(s_cnt, (unsigned int)SORTN);
}

// ============ Kernel 2: bitonic sort (desc) + SSD box decode ============
__global__ __launch_bounds__(1024) void sort_decode_kernel(const unsigned long long* __restrict__ pairs,
                                                           const int* __restrict__ mcount,
                                                           const float* __restrict__ loc,
                                                           const float* __restrict__ prior,
                                                           float4* __restrict__ sboxes,
                                                           float* __restrict__ sscores) {
#pragma clang fp contract(off)
  const int img = blockIdx.x;
  const int tid = threadIdx.x;
  __shared__ unsigned long long key[SORTN];  // 64 KB
  const int M = mcount[img];
  const unsigned long long* mypairs = pairs + (size_t)img * SORTN;
  for (int i = tid; i < SORTN; i += 1024) key[i] = (i < M) ? mypairs[i] : 0ULL;
  __syncthreads();

  // bitonic sort, descending (padding key 0 sinks to the end)
  for (int k = 2; k <= SORTN; k <<= 1) {
    for (int j = k >> 1; j > 0; j >>= 1) {
      for (int i = tid; i < SORTN; i += 1024) {
        int l = i ^ j;
        if (l > i) {
          unsigned long long a = key[i], b = key[l];
          bool sw = ((i & k) == 0) ? (a < b) : (a > b);
          if (sw) { key[i] = b; key[l] = a; }
        }
      }
      __syncthreads();
    }
  }

  // decode top KSEL: exact reference arithmetic, fp32, no contraction
  for (int i = tid; i < KSEL; i += 1024) {
    unsigned long long kk = key[i];
    float score;
    float4 box;
    if (kk != 0ULL) {
      unsigned int u = (unsigned int)(kk >> 32);
      unsigned int p = 0xFFFFFFFFu - (unsigned int)(kk & 0xFFFFFFFFu);
      score = __uint_as_float(u & 0x7FFFFFFFu);
      const float* lp = loc + ((size_t)img * NPRIORS + p) * 4;
      const float* pp = prior + (size_t)p * 4;
      float l0 = lp[0], l1 = lp[1], l2 = lp[2], l3 = lp[3];
      float px = pp[0], py = pp[1], pw = pp[2], ph = pp[3];
      float cx = px + (l0 * 0.1f) * pw;
      float cy = py + (l1 * 0.1f) * ph;
      float w = pw * (float)exp((double)(l2 * 0.2f));
      float hh = ph * (float)exp((double)(l3 * 0.2f));
      box.x = cx - w * 0.5f;
      box.y = cy - hh * 0.5f;
      box.z = cx + w * 0.5f;
      box.w = cy + hh * 0.5f;
    } else {
      score = -1e9f;
      box = make_float4(0.f, 0.f, 0.f, 0.f);
    }
    sboxes[(size_t)img * KSEL + i] = box;
    sscores[(size_t)img * KSEL + i] = score;
  }
}

// ============ Kernel 3a: parallel IoU mask build (torchvision-style) ============
// mask[img][i][w] : bit b set iff j = w*64+b satisfies j>i and IoU(box_i, box_j) > 0.3.
// Block handles rows [strip*64, strip*64+64) x all column tiles at/after the diagonal.
// Words strictly below the first tile are NOT written (sweep zero-fills at load).
__global__ __launch_bounds__(256) void mask_build_kernel(const float4* __restrict__ sboxes,
                                                         unsigned long long* __restrict__ mask) {
#pragma clang fp contract(off)
  const int strip = blockIdx.x;
  const int img = blockIdx.y;
  const int i0 = strip * 64;
  const int tid = threadIdx.x;
  const int lane = tid & 63;
  const int wv = tid >> 6;
  __shared__ float4 ib[64];
  __shared__ float ia[64];
  const float4* bb = sboxes + (size_t)img * KSEL;
  if (tid < 64) {
    int i = i0 + tid;
    float4 b = (i < KSEL) ? bb[i] : make_float4(0.f, 0.f, 0.f, 0.f);
    ib[tid] = b;
    ia[tid] = (b.z - b.x) * (b.w - b.y);
  }
  __syncthreads();
  unsigned long long* mrow = mask + (size_t)img * KSEL * MW;
  for (int jb = (i0 >> 8) << 8; jb < MW * 64; jb += 256) {
    int j = jb + tid;
    float4 cb = (j < KSEL) ? bb[j] : make_float4(0.f, 0.f, 0.f, 0.f);
    float carea = (cb.z - cb.x) * (cb.w - cb.y);
    int wi = (jb >> 6) + wv;
    for (int r = 0; r < 64; ++r) {
      int i = i0 + r;
      float4 pb = ib[r];
      float ltx = fmaxf(pb.x, cb.x), lty = fmaxf(pb.y, cb.y);
      float rbx = fminf(pb.z, cb.z), rby = fminf(pb.w, cb.w);
      float ww = fmaxf(rbx - ltx, 0.0f), hh = fmaxf(rby - lty, 0.0f);
      float inter = ww * hh;
      float uni = ia[r] + carea - inter;
      bool kill = (j > i) && ((inter / fmaxf(uni, 1e-12f)) > 0.3f);
      unsigned long long bal = __ballot(kill);
      if (lane == 0 && i < KSEL) mrow[(size_t)i * MW + wi] = bal;
    }
  }
}

// ============ Kernel 3b: serial greedy sweep — one wave per image, no barriers ============
__global__ __launch_bounds__(64) void sweep_kernel(const unsigned long long* __restrict__ mask,
                                                   const float4* __restrict__ sboxes,
                                                   const float* __restrict__ sscores,
                                                   const int* __restrict__ mcount,
                                                   float* __restrict__ out) {
  const int img = blockIdx.x;
  const int lane = threadIdx.x;
  const int V = min(mcount[img], KSEL);
  const unsigned long long* mb = mask + (size_t)img * KSEL * MW;
  __shared__ int picks[TOPK];
  __shared__ int s_n;

  // remv distributed: lane l owns word l (r0) and word 64+l for l<16 (r1)
  unsigned long long r0 = 0ULL, r1 = 0ULL;
  unsigned long long p0[16], p1[16];
#pragma unroll
  for (int k = 0; k < 16; ++k) {
    int i = k;
    int ftw = (i >> 8) << 2;  // first word written by mask_build for this row
    bool v0 = (i < V) && (lane >= ftw);
    bool v1 = (i < V) && (lane < MW - 64) && ((64 + lane) >= ftw);
    p0[k] = v0 ? mb[(size_t)i * MW + lane] : 0ULL;
    p1[k] = v1 ? mb[(size_t)i * MW + 64 + lane] : 0ULL;
  }
  int nkeep = 0;
  for (int ibase = 0; ibase < V; ibase += 16) {
#pragma unroll
    for (int k = 0; k < 16; ++k) {
      int i = ibase + k;
      if (i < V) {
        unsigned long long m0 = p0[k], m1 = p1[k];
        // prefetch row i+16 into this slot
        int ip = i + 16;
        int ftw = (ip >> 8) << 2;
        bool v0 = (ip < V) && (lane >= ftw);
        bool v1 = (ip < V) && (lane < MW - 64) && ((64 + lane) >= ftw);
        p0[k] = v0 ? mb[(size_t)ip * MW + lane] : 0ULL;
        p1[k] = v1 ? mb[(size_t)ip * MW + 64 + lane] : 0ULL;
        // alive test: bit i of distributed remv
        int w = i >> 6;
        unsigned long long word = (w < 64) ? __shfl(r0, w) : __shfl(r1, w - 64);
        if (!((word >> (i & 63)) & 1ULL)) {
          if (nkeep < TOPK) {
            if (lane == 0) picks[nkeep] = i;
            r0 |= m0;
            r1 |= m1;
          }
          nkeep++;
        }
      }
    }
  }
  if (lane == 0) s_n = min(nkeep, TOPK);
  __syncthreads();
  const int n = s_n;
  float* ob = out + (size_t)img * (2 * TOPK * 5) + TOPK * 5;  // class-1 slab
  for (int k = lane; k < n; k += 64) {
    int i = picks[k];
    float4 b = sboxes[(size_t)img * KSEL + i];
    float sc = sscores[(size_t)img * KSEL + i];
    float* o = ob + (size_t)k * 5;
    o[0] = sc; o[1] = b.x; o[2] = b.y; o[3] = b.z; o[4] = b.w;
  }
}

// ============ Fallback NMS (used only if ws_size is too small for the mask) ============
__global__ __launch_bounds__(1024) void nms_kernel(const float4* __restrict__ sboxes,
                                                   const float* __restrict__ sscores,
                                                   const int* __restrict__ mcount,
                                                   float* __restrict__ out) {
#pragma clang fp contract(off)
  const int img = blockIdx.x;
  const int tid = threadIdx.x;
  __shared__ unsigned long long amask[NMASK];
  __shared__ int s_cur;
  const int V = min(mcount[img], KSEL);

  for (int w = tid; w < NMASK; w += 1024) {
    int lo = w * 64;
    unsigned long long m;
    if (V >= lo + 64)      m = ~0ULL;
    else if (V <= lo)      m = 0ULL;
    else                   m = (~0ULL) >> (64 - (V - lo));
    amask[w] = m;
  }

  const float4* bb = sboxes + (size_t)img * KSEL;
  const float* ss = sscores + (size_t)img * KSEL;
  float4 mybox[5];
  bool alive[5];
  for (int s = 0; s < 5; s++) {
    int c = tid + (s << 10);
    if (c < V) { mybox[s] = bb[c]; alive[s] = true; }
    else       { mybox[s] = make_float4(0.f, 0.f, 0.f, 0.f); alive[s] = false; }
  }
  float* obase = out + (size_t)img * (2 * TOPK * 5) + (TOPK * 5);
  int head = 0;
  __syncthreads();

  for (int k = 0; k < TOPK; k++) {
    if (tid == 0) {
      int idx = -1;
      int w = head >> 6;
      while (w < NMASK) {
        unsigned long long m = amask[w];
        if (m) { idx = (w << 6) + __builtin_ctzll(m); break; }
        w++;
      }
      if (idx >= 0) {
        amask[idx >> 6] &= ~(1ULL << (idx & 63));
        head = idx + 1;
      }
      s_cur = idx;
    }
    __syncthreads();
    const int cidx = s_cur;
    if (cidx < 0) break;
    const float4 pb = bb[cidx];
    if (tid == 0) {
      float* o = obase + k * 5;
      o[0] = ss[cidx]; o[1] = pb.x; o[2] = pb.y; o[3] = pb.z; o[4] = pb.w;
    }
    const float pArea = (pb.z - pb.x) * (pb.w - pb.y);
    for (int s = 0; s < 5; s++) {
      int c = tid + (s << 10);
      if (alive[s] && c > cidx) {
        float4 b = mybox[s];
        float ltx = fmaxf(pb.x, b.x), lty = fmaxf(pb.y, b.y);
        float rbx = fminf(pb.z, b.z), rby = fminf(pb.w, b.w);
        float ww = fmaxf(rbx - ltx, 0.0f), hh2 = fmaxf(rby - lty, 0.0f);
        float inter = ww * hh2;
        float areaB = (b.z - b.x) * (b.w - b.y);
        float uni = pArea + areaB - inter;
        float iou = inter / fmaxf(uni, 1e-12f);
        if (iou > 0.3f) {
          alive[s] = false;
          atomicAnd(&amask[c >> 6], ~(1ULL << (c & 63)));
        }
      }
    }
    __syncthreads();
  }
}

extern "C" void kernel_launch(void* const* d_in, const int* in_sizes, int n_in,
                              void* d_out, int out_size, void* d_ws, size_t ws_size,
                              hipStream_t stream) {
  const float* loc = (const float*)d_in[0];    // [16, 131072, 4]
  const float* conf = (const float*)d_in[1];   // [16*131072, 2]
  const float* prior = (const float*)d_in[2];  // [131072, 4]
  float* out = (float*)d_out;                  // [16, 2, 750, 5]

  char* ws = (char*)d_ws;
  unsigned long long* pairs = (unsigned long long*)(ws + WS_PAIRS);
  int* mcount = (int*)(ws + WS_MCNT);
  float4* sboxes = (float4*)(ws + WS_BOXES);
  float* sscores = (float*)(ws + WS_SCORES);
  unsigned long long* mask = (unsigned long long*)(ws + WS_MASK);

  hipMemsetAsync(d_out, 0, (size_t)out_size * sizeof(float), stream);

  select_kernel<<<NIMG, 1024, 0, stream>>>(conf, pairs, mcount);
  sort_decode_kernel<<<NIMG, 1024, 0, stream>>>(pairs, mcount, loc, prior, sboxes, sscores);

  if (ws_size >= WS_NEEDED) {
    dim3 grid((KSEL + 63) / 64, NIMG);  // 79 x 16
    mask_build_kernel<<<grid, 256, 0, stream>>>(sboxes, mask);
    sweep_kernel<<<NIMG, 64, 0, stream>>>(mask, sboxes, sscores, mcount, out);
  } else {
    nms_kernel<<<NIMG, 1024, 0, stream>>>(sboxes, sscores, mcount, out);
  }
}

// Round 3
// 1941.809 us; speedup vs baseline: 1.1632x; 1.1632x over previous
//
#include <hip/hip_runtime.h>
#include <cmath>

#pragma clang fp contract(off)

typedef unsigned long long ull;

#define NPRIORS 131072
#define NIMG 16
#define KSEL 5000
#define TOPK 750
#define SORTN 8192
#define NBINS 1024
#define NSUB 8
#define NMASK ((KSEL + 63) / 64)   // 79
#define MW 80                      // mask words per row (640 B, 16B-aligned)
#define PFD 32                     // sweep prefetch ring depth

// ---------------- workspace layout ----------------
#define WS_PAIRS 0
#define WS_MCNT 1048576
#define WS_BOXES 1048832
#define WS_SCORES 2328832
#define WS_MASK 2649088
#define WS_NEEDED (WS_MASK + (size_t)NIMG * KSEL * MW * 8)

// ============ Kernel 1: exact top-KSEL selection via 2-level histogram ============
__global__ __launch_bounds__(1024) void select_kernel(const float* __restrict__ conf,
                                                      ull* __restrict__ pairs,
                                                      int* __restrict__ mcount) {
#pragma clang fp contract(off)
  const int img = blockIdx.x;
  const int tid = threadIdx.x;
  __shared__ unsigned int h[NSUB][NBINS];
  __shared__ unsigned int scan[NBINS];
  __shared__ unsigned int s_b1, s_base, s_cutoff, s_cnt;

  const float* cbase = conf + (size_t)img * NPRIORS * 2 + 1;  // class-1 scores, stride 2
  const int sub = (tid >> 6) & (NSUB - 1);

  // ---- pass 1: histogram on u>>22 ----
  for (int i = tid; i < NSUB * NBINS; i += 1024) ((unsigned int*)h)[i] = 0;
  __syncthreads();
  for (int p = tid; p < NPRIORS; p += 1024) {
    float sc = cbase[(size_t)p * 2];
    unsigned int u = (sc > 0.05f) ? (__float_as_uint(sc) | 0x80000000u) : 0u;
    if (u) atomicAdd(&h[sub][u >> 22], 1u);
  }
  __syncthreads();
  unsigned int cnt = 0;
  for (int s = 0; s < NSUB; s++) cnt += h[s][tid];
  scan[tid] = cnt;
  if (tid == 0) s_b1 = 0xFFFFFFFFu;
  __syncthreads();
  for (int off = 1; off < NBINS; off <<= 1) {
    unsigned int v = (tid + off < NBINS) ? scan[tid + off] : 0u;
    __syncthreads();
    scan[tid] += v;
    __syncthreads();
  }
  unsigned int sfx = scan[tid];
  if (sfx >= KSEL && (sfx - cnt) < KSEL) { s_b1 = (unsigned int)tid; s_base = sfx - cnt; }
  __syncthreads();
  unsigned int b1 = s_b1;
  unsigned int cutoff;
  if (b1 == 0xFFFFFFFFu) {
    cutoff = 1u;
  } else {
    // ---- pass 2: refine boundary bin on bits (u>>12)&1023 ----
    for (int i = tid; i < NSUB * NBINS; i += 1024) ((unsigned int*)h)[i] = 0;
    __syncthreads();
    for (int p = tid; p < NPRIORS; p += 1024) {
      float sc = cbase[(size_t)p * 2];
      unsigned int u = (sc > 0.05f) ? (__float_as_uint(sc) | 0x80000000u) : 0u;
      if (u && (u >> 22) == b1) atomicAdd(&h[sub][(u >> 12) & (NBINS - 1)], 1u);
    }
    __syncthreads();
    unsigned int cnt2 = 0;
    for (int s = 0; s < NSUB; s++) cnt2 += h[s][tid];
    scan[tid] = cnt2;
    __syncthreads();
    for (int off = 1; off < NBINS; off <<= 1) {
      unsigned int v = (tid + off < NBINS) ? scan[tid + off] : 0u;
      __syncthreads();
      scan[tid] += v;
      __syncthreads();
    }
    unsigned int base = s_base;
    unsigned int sfx2 = scan[tid];
    if (base + sfx2 >= KSEL && (base + sfx2 - cnt2) < KSEL)
      s_cutoff = (b1 << 22) | ((unsigned int)tid << 12);
    __syncthreads();
    cutoff = s_cutoff;
  }

  // ---- pass 3: compact (u, flipped idx) keys ----
  if (tid == 0) s_cnt = 0;
  __syncthreads();
  ull* mypairs = pairs + (size_t)img * SORTN;
  for (int p = tid; p < NPRIORS; p += 1024) {
    float sc = cbase[(size_t)p * 2];
    unsigned int u = (sc > 0.05f) ? (__float_as_uint(sc) | 0x80000000u) : 0u;
    if (u >= cutoff && u != 0u) {
      unsigned int pos = atomicAdd(&s_cnt, 1u);
      if (pos < SORTN)
        mypairs[pos] = ((ull)u << 32) | (ull)(0xFFFFFFFFu - (unsigned int)p);
    }
  }
  __syncthreads();
  if (tid == 0) mcount[img] = (int)min(s_cnt, (unsigned int)SORTN);
}

// ============ Kernel 2: bitonic sort (desc) + SSD box decode ============
__global__ __launch_bounds__(1024) void sort_decode_kernel(const ull* __restrict__ pairs,
                                                           const int* __restrict__ mcount,
                                                           const float* __restrict__ loc,
                                                           const float* __restrict__ prior,
                                                           float4* __restrict__ sboxes,
                                                           float* __restrict__ sscores) {
#pragma clang fp contract(off)
  const int img = blockIdx.x;
  const int tid = threadIdx.x;
  __shared__ ull key[SORTN];  // 64 KB
  const int M = mcount[img];
  const ull* mypairs = pairs + (size_t)img * SORTN;
  for (int i = tid; i < SORTN; i += 1024) key[i] = (i < M) ? mypairs[i] : 0ULL;
  __syncthreads();

  for (int k = 2; k <= SORTN; k <<= 1) {
    for (int j = k >> 1; j > 0; j >>= 1) {
      for (int i = tid; i < SORTN; i += 1024) {
        int l = i ^ j;
        if (l > i) {
          ull a = key[i], b = key[l];
          bool sw = ((i & k) == 0) ? (a < b) : (a > b);
          if (sw) { key[i] = b; key[l] = a; }
        }
      }
      __syncthreads();
    }
  }

  for (int i = tid; i < KSEL; i += 1024) {
    ull kk = key[i];
    float score;
    float4 box;
    if (kk != 0ULL) {
      unsigned int u = (unsigned int)(kk >> 32);
      unsigned int p = 0xFFFFFFFFu - (unsigned int)(kk & 0xFFFFFFFFu);
      score = __uint_as_float(u & 0x7FFFFFFFu);
      const float* lp = loc + ((size_t)img * NPRIORS + p) * 4;
      const float* pp = prior + (size_t)p * 4;
      float l0 = lp[0], l1 = lp[1], l2 = lp[2], l3 = lp[3];
      float px = pp[0], py = pp[1], pw = pp[2], ph = pp[3];
      float cx = px + (l0 * 0.1f) * pw;
      float cy = py + (l1 * 0.1f) * ph;
      float w = pw * (float)exp((double)(l2 * 0.2f));
      float hh = ph * (float)exp((double)(l3 * 0.2f));
      box.x = cx - w * 0.5f;
      box.y = cy - hh * 0.5f;
      box.z = cx + w * 0.5f;
      box.w = cy + hh * 0.5f;
    } else {
      score = -1e9f;
      box = make_float4(0.f, 0.f, 0.f, 0.f);
    }
    sboxes[(size_t)img * KSEL + i] = box;
    sscores[(size_t)img * KSEL + i] = score;
  }
}

// ============ Kernel 3a: parallel IoU mask build — ALL 80 words written ============
// mask[img][i][w] bit b set iff j=w*64+b has j>i and IoU(box_i,box_j)>0.3.
// Tiles fully below the row strip are zero-stored without computing IoU.
__global__ __launch_bounds__(256) void mask_build_kernel(const float4* __restrict__ sboxes,
                                                         ull* __restrict__ mask) {
#pragma clang fp contract(off)
  const int strip = blockIdx.x;
  const int img = blockIdx.y;
  const int i0 = strip * 64;
  const int tid = threadIdx.x;
  const int lane = tid & 63;
  const int wv = tid >> 6;
  __shared__ float4 ib[64];
  __shared__ float ia[64];
  const float4* bb = sboxes + (size_t)img * KSEL;
  if (tid < 64) {
    int i = i0 + tid;
    float4 b = (i < KSEL) ? bb[i] : make_float4(0.f, 0.f, 0.f, 0.f);
    ib[tid] = b;
    ia[tid] = (b.z - b.x) * (b.w - b.y);
  }
  __syncthreads();
  ull* mrow = mask + (size_t)img * KSEL * MW;
  for (int jb = 0; jb < MW * 64; jb += 256) {
    if (jb + 256 <= i0) {
      // fully below the diagonal strip: zero-fill 64 rows x 4 words
      int r = tid >> 2, wq = tid & 3;
      int i = i0 + r;
      if (i < KSEL) mrow[(size_t)i * MW + (jb >> 6) + wq] = 0ULL;
    } else {
      int j = jb + tid;
      float4 cb = (j < KSEL) ? bb[j] : make_float4(0.f, 0.f, 0.f, 0.f);
      float carea = (cb.z - cb.x) * (cb.w - cb.y);
      int wi = (jb >> 6) + wv;
      for (int r = 0; r < 64; ++r) {
        int i = i0 + r;
        float4 pb = ib[r];
        float ltx = fmaxf(pb.x, cb.x), lty = fmaxf(pb.y, cb.y);
        float rbx = fminf(pb.z, cb.z), rby = fminf(pb.w, cb.w);
        float ww = fmaxf(rbx - ltx, 0.0f), hh = fmaxf(rby - lty, 0.0f);
        float inter = ww * hh;
        float uni = ia[r] + carea - inter;
        bool kill = (j > i) && ((inter / fmaxf(uni, 1e-12f)) > 0.3f);
        ull bal = __ballot(kill);
        if (lane == 0 && i < KSEL) mrow[(size_t)i * MW + wi] = bal;
      }
    }
  }
}

// ============ Kernel 3b: serial greedy sweep — one wave/image, pipelined loads ============
// Lane l (l<40) owns remv words {2l, 2l+1}; one unconditional dwordx4 per row,
// ring-buffered PFD deep. Alive test is scalar against a cached broadcast word,
// refreshed only at 64-boundaries and after picks. Early exit at TOPK picks.
__global__ __launch_bounds__(64) void sweep_kernel(const ull* __restrict__ mask,
                                                   const float4* __restrict__ sboxes,
                                                   const float* __restrict__ sscores,
                                                   const int* __restrict__ mcount,
                                                   float* __restrict__ out) {
  const int img = blockIdx.x;
  const int lane = threadIdx.x;
  const int V = min(mcount[img], KSEL);
  __shared__ int picks[TOPK];
  __shared__ int s_n;
  const ull* mb = mask + (size_t)img * KSEL * MW;
  const int lc = min(lane, 39);

  int nkeep = 0;
  if (V > 0) {
    ull rlo = 0ULL, rhi = 0ULL;   // remv words 2*lane, 2*lane+1
    ull scur = 0ULL;              // broadcast remv word for current i>>6
    ulonglong2 q[PFD];
#pragma unroll
    for (int k = 0; k < PFD; ++k) {
      int ip = (k < V) ? k : (V - 1);
      q[k] = *(const ulonglong2*)(mb + (size_t)ip * MW + 2 * lc);
    }
    for (int ib = 0; ib < V; ib += PFD) {
#pragma unroll
      for (int k = 0; k < PFD; ++k) {
        const int i = ib + k;
        if (i < V) {
          ull m0 = q[k].x, m1 = q[k].y;
          int ip = i + PFD;
          ip = (ip < V) ? ip : (V - 1);
          q[k] = *(const ulonglong2*)(mb + (size_t)ip * MW + 2 * lc);
          const int w = i >> 6;
          if ((i & 63) == 0) {
            ull t = (w & 1) ? rhi : rlo;
            scur = __shfl(t, w >> 1);
          }
          if (!((scur >> (i & 63)) & 1ULL)) {
            if (nkeep < TOPK) {
              if (lane == 0) picks[nkeep] = i;
              rlo |= m0;
              rhi |= m1;
              ull t = (w & 1) ? rhi : rlo;
              scur = __shfl(t, w >> 1);
            }
            nkeep++;
          }
        }
      }
      if (nkeep >= TOPK) break;
    }
  }
  if (lane == 0) s_n = (nkeep < TOPK) ? nkeep : TOPK;
  __syncthreads();
  const int n = s_n;
  float* ob = out + (size_t)img * (2 * TOPK * 5) + TOPK * 5;  // class-1 slab
  for (int k = lane; k < n; k += 64) {
    int i = picks[k];
    float4 b = sboxes[(size_t)img * KSEL + i];
    float sc = sscores[(size_t)img * KSEL + i];
    float* o = ob + (size_t)k * 5;
    o[0] = sc; o[1] = b.x; o[2] = b.y; o[3] = b.z; o[4] = b.w;
  }
}

// ============ Fallback NMS (used only if ws_size too small for the mask) ============
__global__ __launch_bounds__(1024) void nms_kernel(const float4* __restrict__ sboxes,
                                                   const float* __restrict__ sscores,
                                                   const int* __restrict__ mcount,
                                                   float* __restrict__ out) {
#pragma clang fp contract(off)
  const int img = blockIdx.x;
  const int tid = threadIdx.x;
  __shared__ ull amask[NMASK];
  __shared__ int s_cur;
  const int V = min(mcount[img], KSEL);

  for (int w = tid; w < NMASK; w += 1024) {
    int lo = w * 64;
    ull m;
    if (V >= lo + 64)      m = ~0ULL;
    else if (V <= lo)      m = 0ULL;
    else                   m = (~0ULL) >> (64 - (V - lo));
    amask[w] = m;
  }

  const float4* bb = sboxes + (size_t)img * KSEL;
  const float* ss = sscores + (size_t)img * KSEL;
  float4 mybox[5];
  bool alive[5];
  for (int s = 0; s < 5; s++) {
    int c = tid + (s << 10);
    if (c < V) { mybox[s] = bb[c]; alive[s] = true; }
    else       { mybox[s] = make_float4(0.f, 0.f, 0.f, 0.f); alive[s] = false; }
  }
  float* obase = out + (size_t)img * (2 * TOPK * 5) + (TOPK * 5);
  int head = 0;
  __syncthreads();

  for (int k = 0; k < TOPK; k++) {
    if (tid == 0) {
      int idx = -1;
      int w = head >> 6;
      while (w < NMASK) {
        ull m = amask[w];
        if (m) { idx = (w << 6) + __builtin_ctzll(m); break; }
        w++;
      }
      if (idx >= 0) {
        amask[idx >> 6] &= ~(1ULL << (idx & 63));
        head = idx + 1;
      }
      s_cur = idx;
    }
    __syncthreads();
    const int cidx = s_cur;
    if (cidx < 0) break;
    const float4 pb = bb[cidx];
    if (tid == 0) {
      float* o = obase + k * 5;
      o[0] = ss[cidx]; o[1] = pb.x; o[2] = pb.y; o[3] = pb.z; o[4] = pb.w;
    }
    const float pArea = (pb.z - pb.x) * (pb.w - pb.y);
    for (int s = 0; s < 5; s++) {
      int c = tid + (s << 10);
      if (alive[s] && c > cidx) {
        float4 b = mybox[s];
        float ltx = fmaxf(pb.x, b.x), lty = fmaxf(pb.y, b.y);
        float rbx = fminf(pb.z, b.z), rby = fminf(pb.w, b.w);
        float ww = fmaxf(rbx - ltx, 0.0f), hh2 = fmaxf(rby - lty, 0.0f);
        float inter = ww * hh2;
        float areaB = (b.z - b.x) * (b.w - b.y);
        float uni = pArea + areaB - inter;
        float iou = inter / fmaxf(uni, 1e-12f);
        if (iou > 0.3f) {
          alive[s] = false;
          atomicAnd(&amask[c >> 6], ~(1ULL << (c & 63)));
        }
      }
    }
    __syncthreads();
  }
}

extern "C" void kernel_launch(void* const* d_in, const int* in_sizes, int n_in,
                              void* d_out, int out_size, void* d_ws, size_t ws_size,
                              hipStream_t stream) {
  const float* loc = (const float*)d_in[0];    // [16, 131072, 4]
  const float* conf = (const float*)d_in[1];   // [16*131072, 2]
  const float* prior = (const float*)d_in[2];  // [131072, 4]
  float* out = (float*)d_out;                  // [16, 2, 750, 5]

  char* ws = (char*)d_ws;
  ull* pairs = (ull*)(ws + WS_PAIRS);
  int* mcount = (int*)(ws + WS_MCNT);
  float4* sboxes = (float4*)(ws + WS_BOXES);
  float* sscores = (float*)(ws + WS_SCORES);
  ull* mask = (ull*)(ws + WS_MASK);

  hipMemsetAsync(d_out, 0, (size_t)out_size * sizeof(float), stream);

  select_kernel<<<NIMG, 1024, 0, stream>>>(conf, pairs, mcount);
  sort_decode_kernel<<<NIMG, 1024, 0, stream>>>(pairs, mcount, loc, prior, sboxes, sscores);

  if (ws_size >= WS_NEEDED) {
    dim3 grid((KSEL + 63) / 64, NIMG);  // 79 x 16
    mask_build_kernel<<<grid, 256, 0, stream>>>(sboxes, mask);
    sweep_kernel<<<NIMG, 64, 0, stream>>>(mask, sboxes, sscores, mcount, out);
  } else {
    nms_kernel<<<NIMG, 1024, 0, stream>>>(sboxes, sscores, mcount, out);
  }
}

// Round 4
// 840.913 us; speedup vs baseline: 2.6859x; 2.3092x over previous
//
#include <hip/hip_runtime.h>
#include <cmath>

#pragma clang fp contract(off)

typedef unsigned long long ull;

#define NPRIORS 131072
#define NIMG 16
#define KSEL 5000
#define TOPK 750
#define SORTN 8192
#define NBINS 1024
#define NSUB 8
#define NMASK ((KSEL + 63) / 64)   // 79
#define MW 80                      // mask words per row (640 B, 16B-aligned)
#define NCHUNK 79                  // ceil(KSEL/64)
#define KSELP (NCHUNK * 64)        // 5056, diag rows incl. padding

// ---------------- workspace layout ----------------
#define WS_PAIRS 0
#define WS_MCNT 1048576
#define WS_BOXES 1048832
#define WS_SCORES 2328832
#define WS_MASK 2649088
#define WS_DIAG (WS_MASK + (size_t)NIMG * KSEL * MW * 8)        // 53,849,088 (16B aligned)
#define WS_NEEDED (WS_DIAG + (size_t)NIMG * KSELP * 8 + 1024)

// ============ Kernel 1: exact top-KSEL selection via 2-level histogram ============
__global__ __launch_bounds__(1024) void select_kernel(const float* __restrict__ conf,
                                                      ull* __restrict__ pairs,
                                                      int* __restrict__ mcount) {
#pragma clang fp contract(off)
  const int img = blockIdx.x;
  const int tid = threadIdx.x;
  __shared__ unsigned int h[NSUB][NBINS];
  __shared__ unsigned int scan[NBINS];
  __shared__ unsigned int s_b1, s_base, s_cutoff, s_cnt;

  const float* cbase = conf + (size_t)img * NPRIORS * 2 + 1;  // class-1 scores, stride 2
  const int sub = (tid >> 6) & (NSUB - 1);

  // ---- pass 1: histogram on u>>22 ----
  for (int i = tid; i < NSUB * NBINS; i += 1024) ((unsigned int*)h)[i] = 0;
  __syncthreads();
  for (int p = tid; p < NPRIORS; p += 1024) {
    float sc = cbase[(size_t)p * 2];
    unsigned int u = (sc > 0.05f) ? (__float_as_uint(sc) | 0x80000000u) : 0u;
    if (u) atomicAdd(&h[sub][u >> 22], 1u);
  }
  __syncthreads();
  unsigned int cnt = 0;
  for (int s = 0; s < NSUB; s++) cnt += h[s][tid];
  scan[tid] = cnt;
  if (tid == 0) s_b1 = 0xFFFFFFFFu;
  __syncthreads();
  for (int off = 1; off < NBINS; off <<= 1) {
    unsigned int v = (tid + off < NBINS) ? scan[tid + off] : 0u;
    __syncthreads();
    scan[tid] += v;
    __syncthreads();
  }
  unsigned int sfx = scan[tid];
  if (sfx >= KSEL && (sfx - cnt) < KSEL) { s_b1 = (unsigned int)tid; s_base = sfx - cnt; }
  __syncthreads();
  unsigned int b1 = s_b1;
  unsigned int cutoff;
  if (b1 == 0xFFFFFFFFu) {
    cutoff = 1u;
  } else {
    // ---- pass 2: refine boundary bin on bits (u>>12)&1023 ----
    for (int i = tid; i < NSUB * NBINS; i += 1024) ((unsigned int*)h)[i] = 0;
    __syncthreads();
    for (int p = tid; p < NPRIORS; p += 1024) {
      float sc = cbase[(size_t)p * 2];
      unsigned int u = (sc > 0.05f) ? (__float_as_uint(sc) | 0x80000000u) : 0u;
      if (u && (u >> 22) == b1) atomicAdd(&h[sub][(u >> 12) & (NBINS - 1)], 1u);
    }
    __syncthreads();
    unsigned int cnt2 = 0;
    for (int s = 0; s < NSUB; s++) cnt2 += h[s][tid];
    scan[tid] = cnt2;
    __syncthreads();
    for (int off = 1; off < NBINS; off <<= 1) {
      unsigned int v = (tid + off < NBINS) ? scan[tid + off] : 0u;
      __syncthreads();
      scan[tid] += v;
      __syncthreads();
    }
    unsigned int base = s_base;
    unsigned int sfx2 = scan[tid];
    if (base + sfx2 >= KSEL && (base + sfx2 - cnt2) < KSEL)
      s_cutoff = (b1 << 22) | ((unsigned int)tid << 12);
    __syncthreads();
    cutoff = s_cutoff;
  }

  // ---- pass 3: compact (u, flipped idx) keys ----
  if (tid == 0) s_cnt = 0;
  __syncthreads();
  ull* mypairs = pairs + (size_t)img * SORTN;
  for (int p = tid; p < NPRIORS; p += 1024) {
    float sc = cbase[(size_t)p * 2];
    unsigned int u = (sc > 0.05f) ? (__float_as_uint(sc) | 0x80000000u) : 0u;
    if (u >= cutoff && u != 0u) {
      unsigned int pos = atomicAdd(&s_cnt, 1u);
      if (pos < SORTN)
        mypairs[pos] = ((ull)u << 32) | (ull)(0xFFFFFFFFu - (unsigned int)p);
    }
  }
  __syncthreads();
  if (tid == 0) mcount[img] = (int)min(s_cnt, (unsigned int)SORTN);
}

// ============ Kernel 2: bitonic sort (desc) + SSD box decode ============
__global__ __launch_bounds__(1024) void sort_decode_kernel(const ull* __restrict__ pairs,
                                                           const int* __restrict__ mcount,
                                                           const float* __restrict__ loc,
                                                           const float* __restrict__ prior,
                                                           float4* __restrict__ sboxes,
                                                           float* __restrict__ sscores) {
#pragma clang fp contract(off)
  const int img = blockIdx.x;
  const int tid = threadIdx.x;
  __shared__ ull key[SORTN];  // 64 KB
  const int M = mcount[img];
  const ull* mypairs = pairs + (size_t)img * SORTN;
  for (int i = tid; i < SORTN; i += 1024) key[i] = (i < M) ? mypairs[i] : 0ULL;
  __syncthreads();

  for (int k = 2; k <= SORTN; k <<= 1) {
    for (int j = k >> 1; j > 0; j >>= 1) {
      for (int i = tid; i < SORTN; i += 1024) {
        int l = i ^ j;
        if (l > i) {
          ull a = key[i], b = key[l];
          bool sw = ((i & k) == 0) ? (a < b) : (a > b);
          if (sw) { key[i] = b; key[l] = a; }
        }
      }
      __syncthreads();
    }
  }

  for (int i = tid; i < KSEL; i += 1024) {
    ull kk = key[i];
    float score;
    float4 box;
    if (kk != 0ULL) {
      unsigned int u = (unsigned int)(kk >> 32);
      unsigned int p = 0xFFFFFFFFu - (unsigned int)(kk & 0xFFFFFFFFu);
      score = __uint_as_float(u & 0x7FFFFFFFu);
      const float* lp = loc + ((size_t)img * NPRIORS + p) * 4;
      const float* pp = prior + (size_t)p * 4;
      float l0 = lp[0], l1 = lp[1], l2 = lp[2], l3 = lp[3];
      float px = pp[0], py = pp[1], pw = pp[2], ph = pp[3];
      float cx = px + (l0 * 0.1f) * pw;
      float cy = py + (l1 * 0.1f) * ph;
      float w = pw * (float)exp((double)(l2 * 0.2f));
      float hh = ph * (float)exp((double)(l3 * 0.2f));
      box.x = cx - w * 0.5f;
      box.y = cy - hh * 0.5f;
      box.z = cx + w * 0.5f;
      box.w = cy + hh * 0.5f;
    } else {
      score = -1e9f;
      box = make_float4(0.f, 0.f, 0.f, 0.f);
    }
    sboxes[(size_t)img * KSEL + i] = box;
    sscores[(size_t)img * KSEL + i] = score;
  }
}

// ============ Kernel 3a: parallel IoU mask build + compact diagonal ============
// mask[img][i][w] bit b set iff j=w*64+b has j>i and IoU(box_i,box_j)>0.3.
// diag[img][i] = mask word (i>>6) of row i (the intra-chunk 64x64 block, compact).
__global__ __launch_bounds__(256) void mask_build_kernel(const float4* __restrict__ sboxes,
                                                         ull* __restrict__ mask,
                                                         ull* __restrict__ diag) {
#pragma clang fp contract(off)
  const int strip = blockIdx.x;
  const int img = blockIdx.y;
  const int i0 = strip * 64;
  const int tid = threadIdx.x;
  const int lane = tid & 63;
  const int wv = tid >> 6;
  __shared__ float4 ib[64];
  __shared__ float ia[64];
  const float4* bb = sboxes + (size_t)img * KSEL;
  if (tid < 64) {
    int i = i0 + tid;
    float4 b = (i < KSEL) ? bb[i] : make_float4(0.f, 0.f, 0.f, 0.f);
    ib[tid] = b;
    ia[tid] = (b.z - b.x) * (b.w - b.y);
  }
  __syncthreads();
  ull* mrow = mask + (size_t)img * KSEL * MW;
  ull* dg = diag + (size_t)img * KSELP;
  for (int jb = 0; jb < MW * 64; jb += 256) {
    if (jb + 256 <= i0) {
      // fully below the diagonal strip: zero-fill 64 rows x 4 words
      int r = tid >> 2, wq = tid & 3;
      int i = i0 + r;
      if (i < KSEL) mrow[(size_t)i * MW + (jb >> 6) + wq] = 0ULL;
    } else {
      int j = jb + tid;
      float4 cb = (j < KSEL) ? bb[j] : make_float4(0.f, 0.f, 0.f, 0.f);
      float carea = (cb.z - cb.x) * (cb.w - cb.y);
      int wi = (jb >> 6) + wv;
      for (int r = 0; r < 64; ++r) {
        int i = i0 + r;
        float4 pb = ib[r];
        float ltx = fmaxf(pb.x, cb.x), lty = fmaxf(pb.y, cb.y);
        float rbx = fminf(pb.z, cb.z), rby = fminf(pb.w, cb.w);
        float ww = fmaxf(rbx - ltx, 0.0f), hh = fmaxf(rby - lty, 0.0f);
        float inter = ww * hh;
        float uni = ia[r] + carea - inter;
        bool kill = (j > i) && ((inter / fmaxf(uni, 1e-12f)) > 0.3f);
        ull bal = __ballot(kill);
        if (lane == 0 && i < KSEL) {
          mrow[(size_t)i * MW + wi] = bal;
          if (wi == strip) dg[i] = bal;
        }
      }
    }
  }
}

// ============ Kernel 3b: serial greedy sweep — diag-driven, pick-only row loads ============
// One wave/image. Per 64-row chunk: broadcast remv word (1 shfl); ctz-walk survivors
// using the LDS-resident diagonal blocks (register-only); OR the ~10 picked rows'
// full masks in batches of 8 pipelined dwordx4 loads (asm fence stops compiler sinking).
__global__ __launch_bounds__(64) void sweep_kernel(const ull* __restrict__ mask,
                                                   const ull* __restrict__ diag,
                                                   const float4* __restrict__ sboxes,
                                                   const float* __restrict__ sscores,
                                                   const int* __restrict__ mcount,
                                                   float* __restrict__ out) {
  const int img = blockIdx.x;
  const int lane = threadIdx.x;
  const int V = min(mcount[img], KSEL);
  const ull* mb = mask + (size_t)img * KSEL * MW;
  const ull* dg = diag + (size_t)img * KSELP;
  __shared__ ull sdiag[KSELP];   // 40448 B
  __shared__ int picks[TOPK];
  __shared__ int s_n;
  const int lc = min(lane, 39);  // lane-owned mask words {2lc, 2lc+1}

  // preload diag to LDS (coalesced ulonglong2 streaming copy; independent loads)
  for (int o = lane * 2; o < KSELP; o += 128)
    *(ulonglong2*)&sdiag[o] = *(const ulonglong2*)&dg[o];
  __syncthreads();

  ull rlo = 0ULL, rhi = 0ULL;  // remv words 2*lc, 2*lc+1
  int nkeep = 0;

  for (int c = 0; c * 64 < V; ++c) {
    const int base = c * 64;
    // broadcast remv word c
    ull t = (c & 1) ? rhi : rlo;
    ull cur = __shfl(t, c >> 1);
    const ull dw = sdiag[base + lane];  // my row's diagonal word
    const int lim = V - base;
    ull validm = (lim >= 64) ? ~0ULL : ((~0ULL) >> (64 - lim));
    ull avail = (~cur) & validm;

    int nb = 0;
    bool full = false;
    while (avail != 0ULL) {
      int r = __builtin_ctzll(avail);
      int row = base + r;
      if (lane == 0) picks[nkeep] = row;
      nkeep++; nb++;
      if (nkeep >= TOPK) { full = true; break; }
      ull dr = __shfl(dw, r);  // kills within this word from picked row
      avail &= ~(dr | (1ULL << r));
      if (nb == 8) {
        // flush batch of 8: pipelined loads, fence, OR
        int start = nkeep - 8;
        ulonglong2 a[8];
#pragma unroll
        for (int q = 0; q < 8; ++q) {
          int rowq = picks[start + q];
          a[q] = *(const ulonglong2*)(mb + (size_t)rowq * MW + 2 * lc);
        }
        asm volatile("" ::: "memory");
#pragma unroll
        for (int q = 0; q < 8; ++q) { rlo |= a[q].x; rhi |= a[q].y; }
        nb = 0;
      }
    }
    if (full) break;  // picked TOPK: no more decisions needed
    if (nb > 0) {
      int start = nkeep - nb;
      ulonglong2 a[8];
#pragma unroll
      for (int q = 0; q < 8; ++q) {
        int rowq = picks[start + min(q, nb - 1)];  // clamp: safe duplicate loads
        a[q] = *(const ulonglong2*)(mb + (size_t)rowq * MW + 2 * lc);
      }
      asm volatile("" ::: "memory");
#pragma unroll
      for (int q = 0; q < 8; ++q)
        if (q < nb) { rlo |= a[q].x; rhi |= a[q].y; }
    }
  }

  if (lane == 0) s_n = (nkeep < TOPK) ? nkeep : TOPK;
  __syncthreads();
  const int n = s_n;
  float* ob = out + (size_t)img * (2 * TOPK * 5) + TOPK * 5;  // class-1 slab
  for (int k = lane; k < n; k += 64) {
    int i = picks[k];
    float4 b = sboxes[(size_t)img * KSEL + i];
    float sc = sscores[(size_t)img * KSEL + i];
    float* o = ob + (size_t)k * 5;
    o[0] = sc; o[1] = b.x; o[2] = b.y; o[3] = b.z; o[4] = b.w;
  }
}

// ============ Fallback NMS (used only if ws_size too small for the mask) ============
__global__ __launch_bounds__(1024) void nms_kernel(const float4* __restrict__ sboxes,
                                                   const float* __restrict__ sscores,
                                                   const int* __restrict__ mcount,
                                                   float* __restrict__ out) {
#pragma clang fp contract(off)
  const int img = blockIdx.x;
  const int tid = threadIdx.x;
  __shared__ ull amask[NMASK];
  __shared__ int s_cur;
  const int V = min(mcount[img], KSEL);

  for (int w = tid; w < NMASK; w += 1024) {
    int lo = w * 64;
    ull m;
    if (V >= lo + 64)      m = ~0ULL;
    else if (V <= lo)      m = 0ULL;
    else                   m = (~0ULL) >> (64 - (V - lo));
    amask[w] = m;
  }

  const float4* bb = sboxes + (size_t)img * KSEL;
  const float* ss = sscores + (size_t)img * KSEL;
  float4 mybox[5];
  bool alive[5];
  for (int s = 0; s < 5; s++) {
    int c = tid + (s << 10);
    if (c < V) { mybox[s] = bb[c]; alive[s] = true; }
    else       { mybox[s] = make_float4(0.f, 0.f, 0.f, 0.f); alive[s] = false; }
  }
  float* obase = out + (size_t)img * (2 * TOPK * 5) + (TOPK * 5);
  int head = 0;
  __syncthreads();

  for (int k = 0; k < TOPK; k++) {
    if (tid == 0) {
      int idx = -1;
      int w = head >> 6;
      while (w < NMASK) {
        ull m = amask[w];
        if (m) { idx = (w << 6) + __builtin_ctzll(m); break; }
        w++;
      }
      if (idx >= 0) {
        amask[idx >> 6] &= ~(1ULL << (idx & 63));
        head = idx + 1;
      }
      s_cur = idx;
    }
    __syncthreads();
    const int cidx = s_cur;
    if (cidx < 0) break;
    const float4 pb = bb[cidx];
    if (tid == 0) {
      float* o = obase + k * 5;
      o[0] = ss[cidx]; o[1] = pb.x; o[2] = pb.y; o[3] = pb.z; o[4] = pb.w;
    }
    const float pArea = (pb.z - pb.x) * (pb.w - pb.y);
    for (int s = 0; s < 5; s++) {
      int c = tid + (s << 10);
      if (alive[s] && c > cidx) {
        float4 b = mybox[s];
        float ltx = fmaxf(pb.x, b.x), lty = fmaxf(pb.y, b.y);
        float rbx = fminf(pb.z, b.z), rby = fminf(pb.w, b.w);
        float ww = fmaxf(rbx - ltx, 0.0f), hh2 = fmaxf(rby - lty, 0.0f);
        float inter = ww * hh2;
        float areaB = (b.z - b.x) * (b.w - b.y);
        float uni = pArea + areaB - inter;
        float iou = inter / fmaxf(uni, 1e-12f);
        if (iou > 0.3f) {
          alive[s] = false;
          atomicAnd(&amask[c >> 6], ~(1ULL << (c & 63)));
        }
      }
    }
    __syncthreads();
  }
}

extern "C" void kernel_launch(void* const* d_in, const int* in_sizes, int n_in,
                              void* d_out, int out_size, void* d_ws, size_t ws_size,
                              hipStream_t stream) {
  const float* loc = (const float*)d_in[0];    // [16, 131072, 4]
  const float* conf = (const float*)d_in[1];   // [16*131072, 2]
  const float* prior = (const float*)d_in[2];  // [131072, 4]
  float* out = (float*)d_out;                  // [16, 2, 750, 5]

  char* ws = (char*)d_ws;
  ull* pairs = (ull*)(ws + WS_PAIRS);
  int* mcount = (int*)(ws + WS_MCNT);
  float4* sboxes = (float4*)(ws + WS_BOXES);
  float* sscores = (float*)(ws + WS_SCORES);
  ull* mask = (ull*)(ws + WS_MASK);
  ull* diag = (ull*)(ws + WS_DIAG);

  hipMemsetAsync(d_out, 0, (size_t)out_size * sizeof(float), stream);

  select_kernel<<<NIMG, 1024, 0, stream>>>(conf, pairs, mcount);
  sort_decode_kernel<<<NIMG, 1024, 0, stream>>>(pairs, mcount, loc, prior, sboxes, sscores);

  if (ws_size >= WS_NEEDED) {
    dim3 grid((KSEL + 63) / 64, NIMG);  // 79 x 16
    mask_build_kernel<<<grid, 256, 0, stream>>>(sboxes, mask, diag);
    sweep_kernel<<<NIMG, 64, 0, stream>>>(mask, diag, sboxes, sscores, mcount, out);
  } else {
    nms_kernel<<<NIMG, 1024, 0, stream>>>(sboxes, sscores, mcount, out);
  }
}

// Round 5
// 707.398 us; speedup vs baseline: 3.1929x; 1.1887x over previous
//
#include <hip/hip_runtime.h>
#include <cmath>

#pragma clang fp contract(off)

typedef unsigned long long ull;

#define NPRIORS 131072
#define NIMG 16
#define KSEL 5000
#define TOPK 750
#define SORTN 8192
#define MW 80                      // mask words per row (640 B, 16B-aligned)
#define NCHUNK 79
#define KSELP (NCHUNK * 64)        // 5056
#define NBIN 65536

// Exact midpoint between 0.3f and nextafterf(0.3f): fl32(inter/u) > 0.3f
// <=> (double)inter > MID03 * (double)u   (25b x 24b product exact in double;
// tie at midpoint rounds to even mantissa 0x...9A = 0.3f, i.e. NOT >).
#define MID03 0.30000002682209014892578125

// ---------------- workspace layout ----------------
#define WS_PAIRS 0                                   // u64 [16][8192]   1 MB
#define WS_MCNT 1048576                              // int [64]: [0..15]=mcount, [16..31]=cutbin
#define WS_BOXES 1048832                             // f4  [16][5000]
#define WS_SCORES 2328832                            // f32 [16][5000]
#define WS_MASK 2649088                              // u64 [16][5000][80]  51.2 MB
#define WS_HIST (WS_MASK)                            // u32 [16][65536] (aliased, used pre-mask)
#define WS_POS  (WS_MASK + 4194304)                  // u32 [16][65536]
#define WS_CNT  (WS_MASK + 8388608)                  // u32 [16][65536]
#define WS_DIAG (WS_MASK + (size_t)NIMG * KSEL * MW * 8)   // 53,849,088

// ============ Kernel 1: histogram on bin = (bits>>12)&0xFFFF ============
// All scores >0.05 have exponent in [122,126]; bits 12..27 (5 exp + 11 mantissa)
// are strictly monotone in the float value over that set.
__global__ __launch_bounds__(256) void hist_kernel(const float* __restrict__ conf,
                                                   unsigned int* __restrict__ hist) {
  const int img = blockIdx.y;
  const float2* c2 = (const float2*)conf + (size_t)img * NPRIORS;
  unsigned int* H = hist + (size_t)img * NBIN;
  for (int p = blockIdx.x * 256 + threadIdx.x; p < NPRIORS; p += 128 * 256) {
    float sc = c2[p].y;
    if (sc > 0.05f) {
      unsigned int u = __float_as_uint(sc);
      atomicAdd(&H[(u >> 12) & 0xFFFFu], 1u);
    }
  }
}

// ============ Kernel 2: per-image suffix scan -> cutoff bin + bin bases; defaults ============
__global__ __launch_bounds__(1024) void cutoff_kernel(const unsigned int* __restrict__ hist,
                                                      unsigned int* __restrict__ pos,
                                                      int* __restrict__ meta,
                                                      float4* __restrict__ sboxes,
                                                      float* __restrict__ sscores) {
  const int img = blockIdx.x;
  const int tid = threadIdx.x;
  const unsigned int* H = hist + (size_t)img * NBIN;
  unsigned int* P = pos + (size_t)img * NBIN;
  __shared__ unsigned int scan[1024];
  __shared__ unsigned int s_cut;

  const int b0 = tid * 64;
  unsigned int csum = 0;
  for (int k = 0; k < 64; ++k) csum += H[b0 + k];
  scan[tid] = csum;
  if (tid == 0) s_cut = 0;
  __syncthreads();
  for (int off = 1; off < 1024; off <<= 1) {
    unsigned int v = (tid + off < 1024) ? scan[tid + off] : 0u;
    __syncthreads();
    scan[tid] += v;
    __syncthreads();
  }
  unsigned int X = scan[tid] - csum;  // elements in chunks strictly after mine
  // per-bin exclusive-suffix positions, high bin -> low bin
  unsigned int acc = X;
  for (int k = 63; k >= 0; --k) {
    int b = b0 + k;
    unsigned int h = H[b];
    P[b] = acc;
    if (acc < KSEL && acc + h >= KSEL) s_cut = (unsigned int)b;  // unique crossing bin
    acc += h;
  }
  __syncthreads();
  if (tid == 0) {
    unsigned int C = s_cut;
    unsigned int mc = P[C] + H[C];
    meta[img] = (int)min(mc, (unsigned int)SORTN);
    meta[16 + img] = (int)C;
  }
  // default fill (overwritten by rank_decode for real slots)
  for (int i = tid; i < KSEL; i += 1024) {
    sboxes[(size_t)img * KSEL + i] = make_float4(0.f, 0.f, 0.f, 0.f);
    sscores[(size_t)img * KSEL + i] = -1e9f;
  }
}

// ============ Kernel 3: scatter candidates to bin-grouped slots ============
__global__ __launch_bounds__(256) void scatter_kernel(const float* __restrict__ conf,
                                                      const unsigned int* __restrict__ pos,
                                                      unsigned int* __restrict__ cnt,
                                                      const int* __restrict__ meta,
                                                      ull* __restrict__ pairs) {
  const int img = blockIdx.y;
  const float2* c2 = (const float2*)conf + (size_t)img * NPRIORS;
  const unsigned int* P = pos + (size_t)img * NBIN;
  unsigned int* Cn = cnt + (size_t)img * NBIN;
  ull* mypairs = pairs + (size_t)img * SORTN;
  const unsigned int cutval = ((unsigned int)meta[16 + img]) << 12;
  for (int p = blockIdx.x * 256 + threadIdx.x; p < NPRIORS; p += 128 * 256) {
    float sc = c2[p].y;
    if (sc > 0.05f) {
      unsigned int u = __float_as_uint(sc);
      if (u >= cutval) {
        unsigned int bin = (u >> 12) & 0xFFFFu;
        unsigned int slot = atomicAdd(&Cn[bin], 1u);
        unsigned int idx = P[bin] + slot;
        if (idx < SORTN)
          mypairs[idx] = ((ull)u << 32) | (ull)(0xFFFFFFFFu - (unsigned int)p);
      }
    }
  }
}

// ============ Kernel 4: rank within bin (exact order) + SSD decode ============
__global__ __launch_bounds__(256) void rank_decode_kernel(const ull* __restrict__ pairs,
                                                          const unsigned int* __restrict__ hist,
                                                          const unsigned int* __restrict__ pos,
                                                          const int* __restrict__ meta,
                                                          const float* __restrict__ loc,
                                                          const float* __restrict__ prior,
                                                          float4* __restrict__ sboxes,
                                                          float* __restrict__ sscores) {
#pragma clang fp contract(off)
  const int img = blockIdx.y;
  const int s = blockIdx.x * 256 + threadIdx.x;
  const int mc = meta[img];
  if (s >= mc) return;
  const ull* mypairs = pairs + (size_t)img * SORTN;
  const ull key = mypairs[s];
  const unsigned int u = (unsigned int)(key >> 32);
  const unsigned int bin = (u >> 12) & 0xFFFFu;
  const unsigned int base = pos[(size_t)img * NBIN + bin];
  const unsigned int cb = hist[(size_t)img * NBIN + bin];
  const int end = min((int)(base + cb), mc);
  int rank = 0;
  for (int j = (int)base; j < end; ++j) rank += (mypairs[j] > key);
  const int fp = (int)base + rank;
  if (fp >= KSEL) return;
  const unsigned int p = 0xFFFFFFFFu - (unsigned int)(key & 0xFFFFFFFFu);
  const float* lp = loc + ((size_t)img * NPRIORS + p) * 4;
  const float* pp = prior + (size_t)p * 4;
  float l0 = lp[0], l1 = lp[1], l2 = lp[2], l3 = lp[3];
  float px = pp[0], py = pp[1], pw = pp[2], ph = pp[3];
  float cx = px + (l0 * 0.1f) * pw;
  float cy = py + (l1 * 0.1f) * ph;
  float w = pw * (float)exp((double)(l2 * 0.2f));
  float hh = ph * (float)exp((double)(l3 * 0.2f));
  float4 box;
  box.x = cx - w * 0.5f;
  box.y = cy - hh * 0.5f;
  box.z = cx + w * 0.5f;
  box.w = cy + hh * 0.5f;
  sboxes[(size_t)img * KSEL + fp] = box;
  sscores[(size_t)img * KSEL + fp] = __uint_as_float(u);
}

// ============ Kernel 5: IoU mask build — one 64x256 tile per block ============
// mask[img][i][w] bit b set iff j=w*64+b has j>i and fl(inter/union)>0.3f.
// Words with index < 4*(strip>>2) are NEVER written (garbage): the sweep only
// ORs a picked row's words into remv slots consumed for chunks > chunk(row),
// and all words >= 4*(strip>>2) are computed, so garbage is never consumed.
__global__ __launch_bounds__(256) void mask_build_kernel(const float4* __restrict__ sboxes,
                                                         ull* __restrict__ mask,
                                                         ull* __restrict__ diag) {
#pragma clang fp contract(off)
  const int jt = blockIdx.x;       // 0..19  (column tile of 256)
  const int strip = blockIdx.y;    // 0..78  (row chunk of 64)
  const int img = blockIdx.z;
  if (jt < (strip >> 2)) return;   // strictly below diagonal: skip (no zero-fill)
  const int i0 = strip * 64;
  const int tid = threadIdx.x;
  const int lane = tid & 63;
  const int wv = tid >> 6;
  __shared__ float4 ib[64];
  __shared__ float ia[64];
  const float4* bb = sboxes + (size_t)img * KSEL;
  if (tid < 64) {
    int i = i0 + tid;
    float4 b = (i < KSEL) ? bb[i] : make_float4(0.f, 0.f, 0.f, 0.f);
    ib[tid] = b;
    ia[tid] = (b.z - b.x) * (b.w - b.y);
  }
  __syncthreads();
  const int j = jt * 256 + tid;
  float4 cb = (j < KSEL) ? bb[j] : make_float4(0.f, 0.f, 0.f, 0.f);
  const float carea = (cb.z - cb.x) * (cb.w - cb.y);
  const int wi = jt * 4 + wv;
  const bool nodiag = (jt != (strip >> 2));  // whole tile strictly above diagonal
  ull* mrow = mask + (size_t)img * KSEL * MW;
  ull* dg = diag + (size_t)img * KSELP;
  const bool dowrite = (lane == 0);
  const bool isdiagw = (wi == strip);
  for (int r = 0; r < 64; ++r) {
    const int i = i0 + r;
    const float4 pb = ib[r];
    float ltx = fmaxf(pb.x, cb.x), lty = fmaxf(pb.y, cb.y);
    float rbx = fminf(pb.z, cb.z), rby = fminf(pb.w, cb.w);
    float ww = fmaxf(rbx - ltx, 0.0f), hh = fmaxf(rby - lty, 0.0f);
    float inter = ww * hh;
    float uni = fmaxf(ia[r] + carea - inter, 1e-12f);
    bool kill = (nodiag || (j > i)) && ((double)inter > MID03 * (double)uni);
    ull bal = __ballot(kill);
    if (dowrite && i < KSEL) {
      mrow[(size_t)i * MW + wi] = bal;
      if (isdiagw) dg[i] = bal;
    }
  }
}

// ============ Kernel 6: serial greedy sweep — diag-driven, pick-only row loads ============
__global__ __launch_bounds__(64) void sweep_kernel(const ull* __restrict__ mask,
                                                   const ull* __restrict__ diag,
                                                   const float4* __restrict__ sboxes,
                                                   const float* __restrict__ sscores,
                                                   const int* __restrict__ meta,
                                                   float* __restrict__ out) {
  const int img = blockIdx.x;
  const int lane = threadIdx.x;
  const int V = min(meta[img], KSEL);
  const ull* mb = mask + (size_t)img * KSEL * MW;
  const ull* dg = diag + (size_t)img * KSELP;
  __shared__ ull sdiag[KSELP];   // 40448 B
  __shared__ int picks[TOPK];
  __shared__ int s_n;
  const int lc = min(lane, 39);  // lane-owned mask words {2lc, 2lc+1}

  for (int o = lane * 2; o < KSELP; o += 128)
    *(ulonglong2*)&sdiag[o] = *(const ulonglong2*)&dg[o];
  __syncthreads();

  ull rlo = 0ULL, rhi = 0ULL;  // remv words 2*lc, 2*lc+1
  int nkeep = 0;

  for (int c = 0; c * 64 < V; ++c) {
    const int base = c * 64;
    ull t = (c & 1) ? rhi : rlo;
    ull cur = __shfl(t, c >> 1);
    const ull dw = sdiag[base + lane];
    const int lim = V - base;
    ull validm = (lim >= 64) ? ~0ULL : ((~0ULL) >> (64 - lim));
    ull avail = (~cur) & validm;

    int nb = 0;
    bool full = false;
    while (avail != 0ULL) {
      int r = __builtin_ctzll(avail);
      int row = base + r;
      if (lane == 0) picks[nkeep] = row;
      nkeep++; nb++;
      if (nkeep >= TOPK) { full = true; break; }
      ull dr = __shfl(dw, r);
      avail &= ~(dr | (1ULL << r));
      if (nb == 8) {
        int start = nkeep - 8;
        ulonglong2 a[8];
#pragma unroll
        for (int q = 0; q < 8; ++q) {
          int rowq = picks[start + q];
          a[q] = *(const ulonglong2*)(mb + (size_t)rowq * MW + 2 * lc);
        }
        asm volatile("" ::: "memory");
#pragma unroll
        for (int q = 0; q < 8; ++q) { rlo |= a[q].x; rhi |= a[q].y; }
        nb = 0;
      }
    }
    if (full) break;
    if (nb > 0) {
      int start = nkeep - nb;
      ulonglong2 a[8];
#pragma unroll
      for (int q = 0; q < 8; ++q) {
        int rowq = picks[start + min(q, nb - 1)];
        a[q] = *(const ulonglong2*)(mb + (size_t)rowq * MW + 2 * lc);
      }
      asm volatile("" ::: "memory");
#pragma unroll
      for (int q = 0; q < 8; ++q)
        if (q < nb) { rlo |= a[q].x; rhi |= a[q].y; }
    }
  }

  if (lane == 0) s_n = (nkeep < TOPK) ? nkeep : TOPK;
  __syncthreads();
  const int n = s_n;
  float* ob = out + (size_t)img * (2 * TOPK * 5) + TOPK * 5;  // class-1 slab
  for (int k = lane; k < n; k += 64) {
    int i = picks[k];
    float4 b = sboxes[(size_t)img * KSEL + i];
    float sc = sscores[(size_t)img * KSEL + i];
    float* o = ob + (size_t)k * 5;
    o[0] = sc; o[1] = b.x; o[2] = b.y; o[3] = b.z; o[4] = b.w;
  }
}

extern "C" void kernel_launch(void* const* d_in, const int* in_sizes, int n_in,
                              void* d_out, int out_size, void* d_ws, size_t ws_size,
                              hipStream_t stream) {
  const float* loc = (const float*)d_in[0];    // [16, 131072, 4]
  const float* conf = (const float*)d_in[1];   // [16*131072, 2]
  const float* prior = (const float*)d_in[2];  // [131072, 4]
  float* out = (float*)d_out;                  // [16, 2, 750, 5]

  char* ws = (char*)d_ws;
  ull* pairs = (ull*)(ws + WS_PAIRS);
  int* meta = (int*)(ws + WS_MCNT);
  float4* sboxes = (float4*)(ws + WS_BOXES);
  float* sscores = (float*)(ws + WS_SCORES);
  ull* mask = (ull*)(ws + WS_MASK);
  ull* diag = (ull*)(ws + WS_DIAG);
  unsigned int* hist = (unsigned int*)(ws + WS_HIST);
  unsigned int* pos = (unsigned int*)(ws + WS_POS);
  unsigned int* cnt = (unsigned int*)(ws + WS_CNT);

  hipMemsetAsync(d_out, 0, (size_t)out_size * sizeof(float), stream);
  hipMemsetAsync(ws + WS_HIST, 0, 3u * 4194304u, stream);  // hist+pos+cnt

  {
    dim3 g(128, NIMG);
    hist_kernel<<<g, 256, 0, stream>>>(conf, hist);
  }
  cutoff_kernel<<<NIMG, 1024, 0, stream>>>(hist, pos, meta, sboxes, sscores);
  {
    dim3 g(128, NIMG);
    scatter_kernel<<<g, 256, 0, stream>>>(conf, pos, cnt, meta, pairs);
  }
  {
    dim3 g((SORTN + 255) / 256, NIMG);
    rank_decode_kernel<<<g, 256, 0, stream>>>(pairs, hist, pos, meta, loc, prior, sboxes, sscores);
  }
  {
    dim3 g(20, NCHUNK, NIMG);
    mask_build_kernel<<<g, 256, 0, stream>>>(sboxes, mask, diag);
  }
  sweep_kernel<<<NIMG, 64, 0, stream>>>(mask, diag, sboxes, sscores, meta, out);
}

// Round 6
// 643.760 us; speedup vs baseline: 3.5085x; 1.0989x over previous
//
#include <hip/hip_runtime.h>
#include <cmath>

#pragma clang fp contract(off)

typedef unsigned long long ull;

#define NPRIORS 131072
#define NIMG 16
#define KSEL 5000
#define TOPK 750
#define SORTN 8192
#define MW 80                      // mask words per row (640 B, 16B-aligned)
#define NCHUNK 79
#define KSELP (NCHUNK * 64)        // 5056
#define NBIN 65536
#define NSTAGE 16                  // sweep LDS stage slots (rows)

// Exact midpoint between 0.3f and nextafterf(0.3f): fl32(inter/u) > 0.3f
// <=> (double)inter > MID03 * (double)u   (25b x 24b product exact in double;
// tie at midpoint rounds to even mantissa = 0.3f, i.e. NOT >).
#define MID03 0.30000002682209014892578125

// ---------------- workspace layout ----------------
#define WS_PAIRS 0                                   // u64 [16][8192]   1 MB
#define WS_MCNT 1048576                              // int [64]: [0..15]=mcount, [16..31]=cutbin
#define WS_BOXES 1048832                             // f4  [16][5000]
#define WS_SCORES 2328832                            // f32 [16][5000]
#define WS_MASK 2649088                              // u64 [16][5000][80]  51.2 MB
#define WS_HIST (WS_MASK)                            // u32 [16][65536] (aliased, used pre-mask)
#define WS_POS  (WS_MASK + 4194304)                  // u32 [16][65536]
#define WS_CNT  (WS_MASK + 8388608)                  // u32 [16][65536]
#define WS_DIAG (WS_MASK + (size_t)NIMG * KSEL * MW * 8)   // 53,849,088

// ============ Kernel 1: histogram on bin = (bits>>12)&0xFFFF ============
// All scores >0.05 have exponent in [122,126]; bits 12..27 are strictly
// monotone in the float value over that set.
__global__ __launch_bounds__(256) void hist_kernel(const float* __restrict__ conf,
                                                   unsigned int* __restrict__ hist) {
  const int img = blockIdx.y;
  const float4* c4 = (const float4*)conf + (size_t)img * (NPRIORS / 2);
  unsigned int* H = hist + (size_t)img * NBIN;
  for (int q = blockIdx.x * 256 + threadIdx.x; q < NPRIORS / 2; q += 64 * 256) {
    float4 v = c4[q];
    if (v.y > 0.05f) atomicAdd(&H[(__float_as_uint(v.y) >> 12) & 0xFFFFu], 1u);
    if (v.w > 0.05f) atomicAdd(&H[(__float_as_uint(v.w) >> 12) & 0xFFFFu], 1u);
  }
}

// ============ Kernel 2: per-image suffix scan -> cutoff bin + bin bases; defaults ============
__global__ __launch_bounds__(1024) void cutoff_kernel(const unsigned int* __restrict__ hist,
                                                      unsigned int* __restrict__ pos,
                                                      int* __restrict__ meta,
                                                      float4* __restrict__ sboxes,
                                                      float* __restrict__ sscores) {
  const int img = blockIdx.x;
  const int tid = threadIdx.x;
  const unsigned int* H = hist + (size_t)img * NBIN;
  unsigned int* P = pos + (size_t)img * NBIN;
  __shared__ unsigned int scan[1024];
  __shared__ unsigned int s_cut;

  const int b0 = tid * 64;
  unsigned int csum = 0;
  for (int k = 0; k < 64; ++k) csum += H[b0 + k];
  scan[tid] = csum;
  if (tid == 0) s_cut = 0;
  __syncthreads();
  for (int off = 1; off < 1024; off <<= 1) {
    unsigned int v = (tid + off < 1024) ? scan[tid + off] : 0u;
    __syncthreads();
    scan[tid] += v;
    __syncthreads();
  }
  unsigned int X = scan[tid] - csum;  // elements in chunks strictly after mine
  unsigned int acc = X;
  for (int k = 63; k >= 0; --k) {
    int b = b0 + k;
    unsigned int h = H[b];
    P[b] = acc;
    if (acc < KSEL && acc + h >= KSEL) s_cut = (unsigned int)b;  // unique crossing bin
    acc += h;
  }
  __syncthreads();
  if (tid == 0) {
    unsigned int C = s_cut;
    unsigned int mc = P[C] + H[C];
    meta[img] = (int)min(mc, (unsigned int)SORTN);
    meta[16 + img] = (int)C;
  }
  for (int i = tid; i < KSEL; i += 1024) {
    sboxes[(size_t)img * KSEL + i] = make_float4(0.f, 0.f, 0.f, 0.f);
    sscores[(size_t)img * KSEL + i] = -1e9f;
  }
}

// ============ Kernel 3: scatter candidates to bin-grouped slots ============
__global__ __launch_bounds__(256) void scatter_kernel(const float* __restrict__ conf,
                                                      const unsigned int* __restrict__ pos,
                                                      unsigned int* __restrict__ cnt,
                                                      const int* __restrict__ meta,
                                                      ull* __restrict__ pairs) {
  const int img = blockIdx.y;
  const float4* c4 = (const float4*)conf + (size_t)img * (NPRIORS / 2);
  const unsigned int* P = pos + (size_t)img * NBIN;
  unsigned int* Cn = cnt + (size_t)img * NBIN;
  ull* mypairs = pairs + (size_t)img * SORTN;
  const unsigned int cutval = ((unsigned int)meta[16 + img]) << 12;
  for (int q = blockIdx.x * 256 + threadIdx.x; q < NPRIORS / 2; q += 64 * 256) {
    float4 v = c4[q];
#pragma unroll
    for (int h = 0; h < 2; ++h) {
      float sc = h ? v.w : v.y;
      unsigned int p = 2 * (unsigned int)q + h;
      if (sc > 0.05f) {
        unsigned int u = __float_as_uint(sc);
        if (u >= cutval) {
          unsigned int bin = (u >> 12) & 0xFFFFu;
          unsigned int slot = atomicAdd(&Cn[bin], 1u);
          unsigned int idx = P[bin] + slot;
          if (idx < SORTN)
            mypairs[idx] = ((ull)u << 32) | (ull)(0xFFFFFFFFu - p);
        }
      }
    }
  }
}

// ============ Kernel 4: rank within bin (exact order) + SSD decode ============
__global__ __launch_bounds__(256) void rank_decode_kernel(const ull* __restrict__ pairs,
                                                          const unsigned int* __restrict__ hist,
                                                          const unsigned int* __restrict__ pos,
                                                          const int* __restrict__ meta,
                                                          const float* __restrict__ loc,
                                                          const float* __restrict__ prior,
                                                          float4* __restrict__ sboxes,
                                                          float* __restrict__ sscores) {
#pragma clang fp contract(off)
  const int img = blockIdx.y;
  const int s = blockIdx.x * 256 + threadIdx.x;
  const int mc = meta[img];
  if (s >= mc) return;
  const ull* mypairs = pairs + (size_t)img * SORTN;
  const ull key = mypairs[s];
  const unsigned int u = (unsigned int)(key >> 32);
  const unsigned int bin = (u >> 12) & 0xFFFFu;
  const unsigned int base = pos[(size_t)img * NBIN + bin];
  const unsigned int cb = hist[(size_t)img * NBIN + bin];
  const int end = min((int)(base + cb), mc);
  int rank = 0;
  for (int j = (int)base; j < end; ++j) rank += (mypairs[j] > key);
  const int fp = (int)base + rank;
  if (fp >= KSEL) return;
  const unsigned int p = 0xFFFFFFFFu - (unsigned int)(key & 0xFFFFFFFFu);
  const float* lp = loc + ((size_t)img * NPRIORS + p) * 4;
  const float* pp = prior + (size_t)p * 4;
  float l0 = lp[0], l1 = lp[1], l2 = lp[2], l3 = lp[3];
  float px = pp[0], py = pp[1], pw = pp[2], ph = pp[3];
  float cx = px + (l0 * 0.1f) * pw;
  float cy = py + (l1 * 0.1f) * ph;
  float w = pw * (float)exp((double)(l2 * 0.2f));
  float hh = ph * (float)exp((double)(l3 * 0.2f));
  float4 box;
  box.x = cx - w * 0.5f;
  box.y = cy - hh * 0.5f;
  box.z = cx + w * 0.5f;
  box.w = cy + hh * 0.5f;
  sboxes[(size_t)img * KSEL + fp] = box;
  sscores[(size_t)img * KSEL + fp] = __uint_as_float(u);
}

// ============ Kernel 5: IoU mask build — wave-per-row, register word accumulation ============
// mask[img][i][w] bit b set iff j=w*64+b has j>i and fl(inter/union)>0.3f.
// Each block: 64 rows x 256 cols. Wave w owns rows w*16..w*16+15; lanes hold
// the 256 column boxes in registers (4 float4/lane). Lane 0 stores 32
// contiguous bytes per row. Words in groups < strip within the diagonal tile
// are garbage (never consumed: remv word c is read strictly before any
// chunk-c pick's flush); tiles jt < strip>>2 are never written.
__global__ __launch_bounds__(256) void mask_build_kernel(const float4* __restrict__ sboxes,
                                                         ull* __restrict__ mask,
                                                         ull* __restrict__ diag) {
#pragma clang fp contract(off)
  const int jt = blockIdx.x;       // 0..19  (column tile of 256)
  const int strip = blockIdx.y;    // 0..78  (row chunk of 64)
  const int img = blockIdx.z;
  if (jt < (strip >> 2)) return;
  const int i0 = strip * 64;
  const int tid = threadIdx.x;
  const int lane = tid & 63;
  const int wave = tid >> 6;
  __shared__ float4 ib[64];
  const float4* bb = sboxes + (size_t)img * KSEL;
  if (tid < 64) {
    int i = i0 + tid;
    ib[tid] = (i < KSEL) ? bb[i] : make_float4(0.f, 0.f, 0.f, 0.f);
  }
  __syncthreads();
  // column boxes in registers: 4 per lane
  float4 cb[4];
  float ca[4];
#pragma unroll
  for (int s = 0; s < 4; ++s) {
    int j = jt * 256 + s * 64 + lane;
    cb[s] = (j < KSEL) ? bb[j] : make_float4(0.f, 0.f, 0.f, 0.f);
    ca[s] = (cb[s].z - cb[s].x) * (cb[s].w - cb[s].y);
  }
  ull* mrow = mask + (size_t)img * KSEL * MW;
  ull* dg = diag + (size_t)img * KSELP;
  const int grp0 = jt * 4;
  const bool hasdiag = ((strip >> 2) == jt);
  for (int k = 0; k < 16; ++k) {
    const int r = wave * 16 + k;
    const int i = i0 + r;
    const float4 pb = ib[r];
    const float pa = (pb.z - pb.x) * (pb.w - pb.y);
    ull w[4];
#pragma unroll
    for (int s = 0; s < 4; ++s) {
      float ltx = fmaxf(pb.x, cb[s].x), lty = fmaxf(pb.y, cb[s].y);
      float rbx = fminf(pb.z, cb[s].z), rby = fminf(pb.w, cb[s].w);
      float ww = fmaxf(rbx - ltx, 0.0f), hh = fmaxf(rby - lty, 0.0f);
      float inter = ww * hh;
      float uni = fmaxf(pa + ca[s] - inter, 1e-12f);
      bool cond = ((grp0 + s) != strip) | (lane > r);
      bool kill = cond && ((double)inter > MID03 * (double)uni);
      w[s] = __ballot(kill);
    }
    if (lane == 0 && i < KSEL) {
      ull* wp = mrow + (size_t)i * MW + grp0;
      ((ulonglong2*)wp)[0] = make_ulonglong2(w[0], w[1]);
      ((ulonglong2*)wp)[1] = make_ulonglong2(w[2], w[3]);
      if (hasdiag) dg[i] = w[strip & 3];
    }
  }
}

// ============ Kernel 6: serial greedy sweep — LDS-DMA pick prefetch ============
// One wave/image. Per pick: fire global_load_lds (640B row -> LDS stage slot,
// no VGPR round-trip); walk continues on diag (LDS broadcast). At chunk
// boundary: one vmcnt(0) drains all staged rows, OR into register remv.
__global__ __launch_bounds__(64) void sweep_kernel(const ull* __restrict__ mask,
                                                   const ull* __restrict__ diag,
                                                   const float4* __restrict__ sboxes,
                                                   const float* __restrict__ sscores,
                                                   const int* __restrict__ meta,
                                                   float* __restrict__ out) {
  const int img = blockIdx.x;
  const int lane = threadIdx.x;
  const int V = min(meta[img], KSEL);
  const ull* mb = mask + (size_t)img * KSEL * MW;
  const ull* dg = diag + (size_t)img * KSELP;
  __shared__ ull sdiag[KSELP];          // 40448 B
  __shared__ ull stage[NSTAGE * 128];   // 16 KB: 16 slots x 1024 B (64 lanes x 16 B)
  __shared__ int picks[TOPK];
  __shared__ int s_n;
  const int lc = min(lane, 39);  // lane-owned mask words {2lc, 2lc+1}

  for (int o = lane * 2; o < KSELP; o += 128)
    *(ulonglong2*)&sdiag[o] = *(const ulonglong2*)&dg[o];
  __syncthreads();

  ull rlo = 0ULL, rhi = 0ULL;  // remv words 2*lc, 2*lc+1
  int nkeep = 0;

  for (int c = 0; c * 64 < V; ++c) {
    const int base = c * 64;
    ull t = (c & 1) ? rhi : rlo;
    ull cur = __shfl(t, c >> 1);
    const int lim = V - base;
    ull validm = (lim >= 64) ? ~0ULL : ((~0ULL) >> (64 - lim));
    ull avail = (~cur) & validm;

    int nb = 0;
    bool full = false;
    while (avail != 0ULL) {
      int r = __builtin_ctzll(avail);
      int row = base + r;
      if (lane == 0) picks[nkeep] = row;
      nkeep++;
      if (nkeep >= TOPK) { full = true; break; }
      // fire DMA: row's 640B (lanes 40-63 duplicate words 78/79 into their slots)
      __builtin_amdgcn_global_load_lds(
          (const __attribute__((address_space(1))) unsigned int*)(mb + (size_t)row * MW + 2 * lc),
          (__attribute__((address_space(3))) unsigned int*)&stage[nb * 128], 16, 0, 0);
      asm volatile("" ::: "memory");
      nb++;
      ull dr = sdiag[base + r];  // LDS broadcast read
      avail &= ~(dr | (1ULL << r));
      if (nb == NSTAGE) {
        __builtin_amdgcn_s_waitcnt(0xF70);  // vmcnt(0)
        asm volatile("" ::: "memory");
        for (int q = 0; q < NSTAGE; ++q) {
          ulonglong2 v = *(ulonglong2*)&stage[q * 128 + 2 * lane];
          rlo |= v.x; rhi |= v.y;
        }
        nb = 0;
      }
    }
    if (full) break;
    if (nb > 0) {
      __builtin_amdgcn_s_waitcnt(0xF70);  // vmcnt(0)
      asm volatile("" ::: "memory");
      for (int q = 0; q < nb; ++q) {
        ulonglong2 v = *(ulonglong2*)&stage[q * 128 + 2 * lane];
        rlo |= v.x; rhi |= v.y;
      }
    }
  }

  if (lane == 0) s_n = (nkeep < TOPK) ? nkeep : TOPK;
  __syncthreads();
  const int n = s_n;
  float* ob = out + (size_t)img * (2 * TOPK * 5) + TOPK * 5;  // class-1 slab
  for (int k = lane; k < n; k += 64) {
    int i = picks[k];
    float4 b = sboxes[(size_t)img * KSEL + i];
    float sc = sscores[(size_t)img * KSEL + i];
    float* o = ob + (size_t)k * 5;
    o[0] = sc; o[1] = b.x; o[2] = b.y; o[3] = b.z; o[4] = b.w;
  }
}

extern "C" void kernel_launch(void* const* d_in, const int* in_sizes, int n_in,
                              void* d_out, int out_size, void* d_ws, size_t ws_size,
                              hipStream_t stream) {
  const float* loc = (const float*)d_in[0];    // [16, 131072, 4]
  const float* conf = (const float*)d_in[1];   // [16*131072, 2]
  const float* prior = (const float*)d_in[2];  // [131072, 4]
  float* out = (float*)d_out;                  // [16, 2, 750, 5]

  char* ws = (char*)d_ws;
  ull* pairs = (ull*)(ws + WS_PAIRS);
  int* meta = (int*)(ws + WS_MCNT);
  float4* sboxes = (float4*)(ws + WS_BOXES);
  float* sscores = (float*)(ws + WS_SCORES);
  ull* mask = (ull*)(ws + WS_MASK);
  ull* diag = (ull*)(ws + WS_DIAG);
  unsigned int* hist = (unsigned int*)(ws + WS_HIST);
  unsigned int* pos = (unsigned int*)(ws + WS_POS);
  unsigned int* cnt = (unsigned int*)(ws + WS_CNT);

  hipMemsetAsync(d_out, 0, (size_t)out_size * sizeof(float), stream);
  hipMemsetAsync(ws + WS_HIST, 0, 3u * 4194304u, stream);  // hist+pos+cnt

  {
    dim3 g(64, NIMG);
    hist_kernel<<<g, 256, 0, stream>>>(conf, hist);
  }
  cutoff_kernel<<<NIMG, 1024, 0, stream>>>(hist, pos, meta, sboxes, sscores);
  {
    dim3 g(64, NIMG);
    scatter_kernel<<<g, 256, 0, stream>>>(conf, pos, cnt, meta, pairs);
  }
  {
    dim3 g((SORTN + 255) / 256, NIMG);
    rank_decode_kernel<<<g, 256, 0, stream>>>(pairs, hist, pos, meta, loc, prior, sboxes, sscores);
  }
  {
    dim3 g(20, NCHUNK, NIMG);
    mask_build_kernel<<<g, 256, 0, stream>>>(sboxes, mask, diag);
  }
  sweep_kernel<<<NIMG, 64, 0, stream>>>(mask, diag, sboxes, sscores, meta, out);
}

// Round 7
// 601.678 us; speedup vs baseline: 3.7539x; 1.0699x over previous
//
#include <hip/hip_runtime.h>
#include <cmath>

#pragma clang fp contract(off)

typedef unsigned long long ull;

#define NPRIORS 131072
#define NIMG 16
#define KSEL 5000
#define TOPK 750
#define SORTN 8192
#define MW 80                      // mask words per row (640 B, 16B-aligned)
#define NCHUNK 79
#define KSELP (NCHUNK * 64)        // 5056
#define NBIN 65536
#define NSTAGE 16                  // sweep LDS stage slots (rows)

// Exact midpoint between 0.3f and nextafterf(0.3f): fl32(inter/u) > 0.3f
// <=> (double)inter > MID03 * (double)uni  (25b x 24b product exact in double;
// tie at midpoint rounds to even mantissa = 0.3f, i.e. NOT >).
#define MID03 0.30000002682209014892578125

// ---------------- workspace layout ----------------
#define WS_PAIRS 0                                   // u64 [16][8192]   1 MB
#define WS_MCNT 1048576                              // int [64]: [0..15]=mcount, [16..31]=cutbin
#define WS_BOXES 1048832                             // f4  [16][5000]
#define WS_SCORES 2328832                            // f32 [16][5000]
#define WS_MASK 2649088                              // u64 [16][5000][80]  51.2 MB
#define WS_HIST (WS_MASK)                            // u32 [16][65536] (aliased, used pre-mask)
#define WS_POS  (WS_MASK + 4194304)                  // u32 [16][65536]
#define WS_CNT  (WS_MASK + 8388608)                  // u32 [16][65536]
#define WS_DIAG (WS_MASK + (size_t)NIMG * KSEL * MW * 8)   // 53,849,088

// ============ Kernel 1: histogram on bin = (bits>>12)&0xFFFF ============
__global__ __launch_bounds__(256) void hist_kernel(const float* __restrict__ conf,
                                                   unsigned int* __restrict__ hist) {
  const int img = blockIdx.y;
  const float4* c4 = (const float4*)conf + (size_t)img * (NPRIORS / 2);
  unsigned int* H = hist + (size_t)img * NBIN;
  for (int q = blockIdx.x * 256 + threadIdx.x; q < NPRIORS / 2; q += 64 * 256) {
    float4 v = c4[q];
    if (v.y > 0.05f) atomicAdd(&H[(__float_as_uint(v.y) >> 12) & 0xFFFFu], 1u);
    if (v.w > 0.05f) atomicAdd(&H[(__float_as_uint(v.w) >> 12) & 0xFFFFu], 1u);
  }
}

// ============ Kernel 2: per-image suffix scan -> cutoff bin + bin bases; defaults ============
__global__ __launch_bounds__(1024) void cutoff_kernel(const unsigned int* __restrict__ hist,
                                                      unsigned int* __restrict__ pos,
                                                      int* __restrict__ meta,
                                                      float4* __restrict__ sboxes,
                                                      float* __restrict__ sscores) {
  const int img = blockIdx.x;
  const int tid = threadIdx.x;
  const unsigned int* H = hist + (size_t)img * NBIN;
  unsigned int* P = pos + (size_t)img * NBIN;
  __shared__ unsigned int scan[1024];
  __shared__ unsigned int s_cut;

  const int b0 = tid * 64;
  unsigned int csum = 0;
  for (int k = 0; k < 64; ++k) csum += H[b0 + k];
  scan[tid] = csum;
  if (tid == 0) s_cut = 0;
  __syncthreads();
  for (int off = 1; off < 1024; off <<= 1) {
    unsigned int v = (tid + off < 1024) ? scan[tid + off] : 0u;
    __syncthreads();
    scan[tid] += v;
    __syncthreads();
  }
  unsigned int X = scan[tid] - csum;  // elements in chunks strictly after mine
  unsigned int acc = X;
  for (int k = 63; k >= 0; --k) {
    int b = b0 + k;
    unsigned int h = H[b];
    P[b] = acc;
    if (acc < KSEL && acc + h >= KSEL) s_cut = (unsigned int)b;  // unique crossing bin
    acc += h;
  }
  __syncthreads();
  if (tid == 0) {
    unsigned int C = s_cut;
    unsigned int mc = P[C] + H[C];
    meta[img] = (int)min(mc, (unsigned int)SORTN);
    meta[16 + img] = (int)C;
  }
  for (int i = tid; i < KSEL; i += 1024) {
    sboxes[(size_t)img * KSEL + i] = make_float4(0.f, 0.f, 0.f, 0.f);
    sscores[(size_t)img * KSEL + i] = -1e9f;
  }
}

// ============ Kernel 3: scatter candidates to bin-grouped slots ============
__global__ __launch_bounds__(256) void scatter_kernel(const float* __restrict__ conf,
                                                      const unsigned int* __restrict__ pos,
                                                      unsigned int* __restrict__ cnt,
                                                      const int* __restrict__ meta,
                                                      ull* __restrict__ pairs) {
  const int img = blockIdx.y;
  const float4* c4 = (const float4*)conf + (size_t)img * (NPRIORS / 2);
  const unsigned int* P = pos + (size_t)img * NBIN;
  unsigned int* Cn = cnt + (size_t)img * NBIN;
  ull* mypairs = pairs + (size_t)img * SORTN;
  const unsigned int cutval = ((unsigned int)meta[16 + img]) << 12;
  for (int q = blockIdx.x * 256 + threadIdx.x; q < NPRIORS / 2; q += 64 * 256) {
    float4 v = c4[q];
#pragma unroll
    for (int h = 0; h < 2; ++h) {
      float sc = h ? v.w : v.y;
      unsigned int p = 2 * (unsigned int)q + h;
      if (sc > 0.05f) {
        unsigned int u = __float_as_uint(sc);
        if (u >= cutval) {
          unsigned int bin = (u >> 12) & 0xFFFFu;
          unsigned int slot = atomicAdd(&Cn[bin], 1u);
          unsigned int idx = P[bin] + slot;
          if (idx < SORTN)
            mypairs[idx] = ((ull)u << 32) | (ull)(0xFFFFFFFFu - p);
        }
      }
    }
  }
}

// ============ Kernel 4: rank within bin (exact order) + SSD decode ============
__global__ __launch_bounds__(256) void rank_decode_kernel(const ull* __restrict__ pairs,
                                                          const unsigned int* __restrict__ hist,
                                                          const unsigned int* __restrict__ pos,
                                                          const int* __restrict__ meta,
                                                          const float* __restrict__ loc,
                                                          const float* __restrict__ prior,
                                                          float4* __restrict__ sboxes,
                                                          float* __restrict__ sscores) {
#pragma clang fp contract(off)
  const int img = blockIdx.y;
  const int s = blockIdx.x * 256 + threadIdx.x;
  const int mc = meta[img];
  if (s >= mc) return;
  const ull* mypairs = pairs + (size_t)img * SORTN;
  const ull key = mypairs[s];
  const unsigned int u = (unsigned int)(key >> 32);
  const unsigned int bin = (u >> 12) & 0xFFFFu;
  const unsigned int base = pos[(size_t)img * NBIN + bin];
  const unsigned int cb = hist[(size_t)img * NBIN + bin];
  const int end = min((int)(base + cb), mc);
  int rank = 0;
  for (int j = (int)base; j < end; ++j) rank += (mypairs[j] > key);
  const int fp = (int)base + rank;
  if (fp >= KSEL) return;
  const unsigned int p = 0xFFFFFFFFu - (unsigned int)(key & 0xFFFFFFFFu);
  const float* lp = loc + ((size_t)img * NPRIORS + p) * 4;
  const float* pp = prior + (size_t)p * 4;
  float l0 = lp[0], l1 = lp[1], l2 = lp[2], l3 = lp[3];
  float px = pp[0], py = pp[1], pw = pp[2], ph = pp[3];
  float cx = px + (l0 * 0.1f) * pw;
  float cy = py + (l1 * 0.1f) * ph;
  float w = pw * (float)exp((double)(l2 * 0.2f));
  float hh = ph * (float)exp((double)(l3 * 0.2f));
  float4 box;
  box.x = cx - w * 0.5f;
  box.y = cy - hh * 0.5f;
  box.z = cx + w * 0.5f;
  box.w = cy + hh * 0.5f;
  sboxes[(size_t)img * KSEL + fp] = box;
  sscores[(size_t)img * KSEL + fp] = __uint_as_float(u);
}

// ============ Kernel 5: IoU mask build — wave-per-row, register word accumulation ============
__global__ __launch_bounds__(256) void mask_build_kernel(const float4* __restrict__ sboxes,
                                                         ull* __restrict__ mask,
                                                         ull* __restrict__ diag) {
#pragma clang fp contract(off)
  const int jt = blockIdx.x;       // 0..19  (column tile of 256)
  const int strip = blockIdx.y;    // 0..78  (row chunk of 64)
  const int img = blockIdx.z;
  if (jt < (strip >> 2)) return;
  const int i0 = strip * 64;
  const int tid = threadIdx.x;
  const int lane = tid & 63;
  const int wave = tid >> 6;
  __shared__ float4 ib[64];
  const float4* bb = sboxes + (size_t)img * KSEL;
  if (tid < 64) {
    int i = i0 + tid;
    ib[tid] = (i < KSEL) ? bb[i] : make_float4(0.f, 0.f, 0.f, 0.f);
  }
  __syncthreads();
  float4 cb[4];
  float ca[4];
#pragma unroll
  for (int s = 0; s < 4; ++s) {
    int j = jt * 256 + s * 64 + lane;
    cb[s] = (j < KSEL) ? bb[j] : make_float4(0.f, 0.f, 0.f, 0.f);
    ca[s] = (cb[s].z - cb[s].x) * (cb[s].w - cb[s].y);
  }
  ull* mrow = mask + (size_t)img * KSEL * MW;
  ull* dg = diag + (size_t)img * KSELP;
  const int grp0 = jt * 4;
  const bool hasdiag = ((strip >> 2) == jt);
  for (int k = 0; k < 16; ++k) {
    const int r = wave * 16 + k;
    const int i = i0 + r;
    const float4 pb = ib[r];
    const float pa = (pb.z - pb.x) * (pb.w - pb.y);
    ull w[4];
#pragma unroll
    for (int s = 0; s < 4; ++s) {
      float ltx = fmaxf(pb.x, cb[s].x), lty = fmaxf(pb.y, cb[s].y);
      float rbx = fminf(pb.z, cb[s].z), rby = fminf(pb.w, cb[s].w);
      float ww = fmaxf(rbx - ltx, 0.0f), hh = fmaxf(rby - lty, 0.0f);
      float inter = ww * hh;
      float uni = fmaxf(pa + ca[s] - inter, 1e-12f);
      bool cond = ((grp0 + s) != strip) | (lane > r);
      bool kill = cond && ((double)inter > MID03 * (double)uni);
      w[s] = __ballot(kill);
    }
    if (lane == 0 && i < KSEL) {
      ull* wp = mrow + (size_t)i * MW + grp0;
      ((ulonglong2*)wp)[0] = make_ulonglong2(w[0], w[1]);
      ((ulonglong2*)wp)[1] = make_ulonglong2(w[2], w[3]);
      if (hasdiag) dg[i] = w[strip & 3];
    }
  }
}

// ============ Kernel 6: serial greedy sweep — scalar readlane pick walk ============
// One wave/image. Pick walk is pure scalar-ALU: s_ff1 on uniform avail +
// v_readlane (runtime SGPR lane index) of the per-lane diag word. No LDS
// reads, no shfl, no asm barrier inside the loop. Per pick: fire one
// global_load_lds DMA (640B mask row -> LDS stage slot); one vmcnt(0) drain
// per chunk flush ORs staged rows into the register-distributed remv.
__global__ __launch_bounds__(64) void sweep_kernel(const ull* __restrict__ mask,
                                                   const ull* __restrict__ diag,
                                                   const float4* __restrict__ sboxes,
                                                   const float* __restrict__ sscores,
                                                   const int* __restrict__ meta,
                                                   float* __restrict__ out) {
  const int img = blockIdx.x;
  const int lane = threadIdx.x;
  const int V = min(meta[img], KSEL);
  const ull* mb = mask + (size_t)img * KSEL * MW;
  const ull* dg = diag + (size_t)img * KSELP;
  __shared__ ull sdiag[KSELP];          // 40448 B
  __shared__ ull stage[NSTAGE * 128];   // 16 KB: 16 slots x 1024 B (64 lanes x 16 B)
  __shared__ int picks[TOPK];
  __shared__ int s_n;
  const int lc = min(lane, 39);  // lane-owned mask words {2lc, 2lc+1}

  for (int o = lane * 2; o < KSELP; o += 128)
    *(ulonglong2*)&sdiag[o] = *(const ulonglong2*)&dg[o];
  __syncthreads();

  ull rlo = 0ULL, rhi = 0ULL;  // remv words 2*lc, 2*lc+1 (per-lane VGPRs)
  int nkeep = 0;

  ull dw = sdiag[lane];  // chunk 0: my row's diag word
  for (int c = 0; c * 64 < V; ++c) {
    const int base = c * 64;
    // prefetch next chunk's diag word (off critical path)
    ull dwn = sdiag[min(base + 64 + lane, KSELP - 1)];
    // remv word c via readlane (uniform)
    ull t = (c & 1) ? rhi : rlo;
    unsigned cur_lo = (unsigned)__builtin_amdgcn_readlane((int)(unsigned)t, c >> 1);
    unsigned cur_hi = (unsigned)__builtin_amdgcn_readlane((int)(unsigned)(t >> 32), c >> 1);
    ull cur = ((ull)cur_hi << 32) | cur_lo;
    const int lim = V - base;
    ull validm = (lim >= 64) ? ~0ULL : ((~0ULL) >> (64 - lim));
    ull avail = (~cur) & validm;

    int nb = 0;
    bool full = false;
    while (avail != 0ULL) {
      int r = __builtin_ctzll(avail);
      int row = base + r;
      if (lane == 0) picks[nkeep] = row;
      nkeep++;
      if (nkeep >= TOPK) { full = true; break; }
      // fire DMA: row's 640B (lanes 40-63 duplicate words 78/79 into their slots)
      __builtin_amdgcn_global_load_lds(
          (const __attribute__((address_space(1))) unsigned int*)(mb + (size_t)row * MW + 2 * lc),
          (__attribute__((address_space(3))) unsigned int*)&stage[nb * 128], 16, 0, 0);
      nb++;
      // scalar suppression: readlane of the per-lane diag word at lane r
      unsigned dr_lo = (unsigned)__builtin_amdgcn_readlane((int)(unsigned)dw, r);
      unsigned dr_hi = (unsigned)__builtin_amdgcn_readlane((int)(unsigned)(dw >> 32), r);
      ull dr = ((ull)dr_hi << 32) | dr_lo;
      avail &= ~(dr | (1ULL << r));
      if (nb == NSTAGE) {
        __builtin_amdgcn_s_waitcnt(0xF70);  // vmcnt(0)
        asm volatile("" ::: "memory");
        for (int q = 0; q < NSTAGE; ++q) {
          ulonglong2 v = *(ulonglong2*)&stage[q * 128 + 2 * lane];
          rlo |= v.x; rhi |= v.y;
        }
        nb = 0;
      }
    }
    if (full) break;
    if (nb > 0) {
      __builtin_amdgcn_s_waitcnt(0xF70);  // vmcnt(0)
      asm volatile("" ::: "memory");
      for (int q = 0; q < nb; ++q) {
        ulonglong2 v = *(ulonglong2*)&stage[q * 128 + 2 * lane];
        rlo |= v.x; rhi |= v.y;
      }
    }
    dw = dwn;
  }

  if (lane == 0) s_n = (nkeep < TOPK) ? nkeep : TOPK;
  __syncthreads();
  const int n = s_n;
  float* ob = out + (size_t)img * (2 * TOPK * 5) + TOPK * 5;  // class-1 slab
  for (int k = lane; k < n; k += 64) {
    int i = picks[k];
    float4 b = sboxes[(size_t)img * KSEL + i];
    float sc = sscores[(size_t)img * KSEL + i];
    float* o = ob + (size_t)k * 5;
    o[0] = sc; o[1] = b.x; o[2] = b.y; o[3] = b.z; o[4] = b.w;
  }
}

extern "C" void kernel_launch(void* const* d_in, const int* in_sizes, int n_in,
                              void* d_out, int out_size, void* d_ws, size_t ws_size,
                              hipStream_t stream) {
  const float* loc = (const float*)d_in[0];    // [16, 131072, 4]
  const float* conf = (const float*)d_in[1];   // [16*131072, 2]
  const float* prior = (const float*)d_in[2];  // [131072, 4]
  float* out = (float*)d_out;                  // [16, 2, 750, 5]

  char* ws = (char*)d_ws;
  ull* pairs = (ull*)(ws + WS_PAIRS);
  int* meta = (int*)(ws + WS_MCNT);
  float4* sboxes = (float4*)(ws + WS_BOXES);
  float* sscores = (float*)(ws + WS_SCORES);
  ull* mask = (ull*)(ws + WS_MASK);
  ull* diag = (ull*)(ws + WS_DIAG);
  unsigned int* hist = (unsigned int*)(ws + WS_HIST);
  unsigned int* pos = (unsigned int*)(ws + WS_POS);
  unsigned int* cnt = (unsigned int*)(ws + WS_CNT);

  hipMemsetAsync(d_out, 0, (size_t)out_size * sizeof(float), stream);
  hipMemsetAsync(ws + WS_HIST, 0, 3u * 4194304u, stream);  // hist+pos+cnt

  {
    dim3 g(64, NIMG);
    hist_kernel<<<g, 256, 0, stream>>>(conf, hist);
  }
  cutoff_kernel<<<NIMG, 1024, 0, stream>>>(hist, pos, meta, sboxes, sscores);
  {
    dim3 g(64, NIMG);
    scatter_kernel<<<g, 256, 0, stream>>>(conf, pos, cnt, meta, pairs);
  }
  {
    dim3 g((SORTN + 255) / 256, NIMG);
    rank_decode_kernel<<<g, 256, 0, stream>>>(pairs, hist, pos, meta, loc, prior, sboxes, sscores);
  }
  {
    dim3 g(20, NCHUNK, NIMG);
    mask_build_kernel<<<g, 256, 0, stream>>>(sboxes, mask, diag);
  }
  sweep_kernel<<<NIMG, 64, 0, stream>>>(mask, diag, sboxes, sscores, meta, out);
}